// Round 12
// baseline (1104.740 us; speedup 1.0000x reference)
//
#include <hip/hip_runtime.h>
#include <math.h>

namespace {

typedef unsigned short u16;
typedef __attribute__((ext_vector_type(8))) short s8v;
typedef __attribute__((ext_vector_type(8))) unsigned short u16x8;
typedef __attribute__((ext_vector_type(4))) unsigned short u16x4;
typedef __attribute__((ext_vector_type(4))) float f32x4;
typedef __attribute__((ext_vector_type(4))) unsigned int u32x4;

constexpr int HBT = 8192;            // 32*256
constexpr long HHf = 4194304;        // 8192*512

// ---- workspace offsets (float units) ----
constexpr long F_H    = 0;           // h / x_emb fp32 (8388608)
constexpr long F_LNB  = 8388608;     // ln / o / hbf bf16
constexpr long F_QKV  = 12582912;    // qkv bf16; xb during conv; P (bf16) after softmax; ff1 out
constexpr long F_VT   = 25165824;    // v^T bf16
constexpr long F_SC   = 29360128;    // scores fp32 (16777216) -> region ends 46137344
// phase M (QKV/VT/SC regions dead):
constexpr long F_ATT  = 12582912;    // 4 x 491520 fp32: attA, attNA, attAN, attN
constexpr long F_AUG  = 14548992;    // 4 x 4194304 u16: augA, augNA, augAN, augN
constexpr long F_MU   = 22937600;    // fp32 (round1 mu out; vae overwrites with nnew)
constexpr long F_VAR  = 27131904;    // round1 var out
constexpr long F_R0   = 31326208;    // round2: A_aug_new
constexpr long F_R1   = 35520512;    // round2: N_Aaug_m (nam)
constexpr long F_R2   = 39714816;    // round2: A_Naug_m (anm)
// membT overlaps the (dead-by-then) scores region; filled in MEMORY PHASE only.
constexpr long W_MEMB = 43909120;    // bf16 [2][128][512] zero-padded (131072 u16 = 65536 fl)
constexpr long Z_PG   = 43974656;    // zero page (256 u16) — conv phase only
// transposed weights (bf16), live whole launch:
constexpr long W_QKV  = 46137344;    // 2 x 786432 u16
constexpr long W_OUT  = 46923776;    // 2 x 262144 u16
constexpr long W_FF1  = 47185920;
constexpr long W_FF2  = 47448064;
constexpr long W_MU   = 47710208;    // 262144 u16
constexpr long W_VAR  = 47841280;
constexpr long W_CONV = 47972352;    // 1572864 u16
constexpr long W_AMT  = 48758784;    // 32768 u16 (512x64 padded)
constexpr long W_NMT  = 48775168;
constexpr long O_ANC  = 48791552;
constexpr long O_POS  = O_ANC + 16384;
constexpr long O_NEG  = O_POS + 16384;
constexpr long O_ANEW = O_NEG + 16384;
constexpr long O_NNEG = O_ANEW + 16384;
constexpr long O_IDX  = O_NNEG + 16384;   // 3*544 ints
constexpr long O_ACC  = O_IDX + 1632;     // 4 floats

// ---- output offsets ----
constexpr long OO_AATT  = 3;
constexpr long OO_NATT  = 3 + 8192;
constexpr long OO_ANATT = 3 + 16384;
constexpr long OO_NAATT = 3 + 24576;
constexpr long OO_COS   = 32771;
constexpr long OO_XOUT  = 32772;
constexpr long OO_VFEAT = 32772L + 16777216L;

__device__ inline u16 to_bf16(float f) {
  union { float f; unsigned u; } x; x.f = f;
  unsigned r = x.u + 0x7fffu + ((x.u >> 16) & 1u);
  return (u16)(r >> 16);
}
__device__ inline u16x8 pack8(float4 a, float4 b) {
  u16x8 r;
  r[0]=to_bf16(a.x); r[1]=to_bf16(a.y); r[2]=to_bf16(a.z); r[3]=to_bf16(a.w);
  r[4]=to_bf16(b.x); r[5]=to_bf16(b.y); r[6]=to_bf16(b.z); r[7]=to_bf16(b.w);
  return r;
}

// async global->LDS, 16B per lane; LDS dest = wave-uniform base + lane*16
typedef __attribute__((address_space(1))) void gvoid;
typedef __attribute__((address_space(3))) void lvoid;
__device__ inline void gld16(const u16* g, u16* l) {
  __builtin_amdgcn_global_load_lds((gvoid*)g, (lvoid*)l, 16, 0, 0);
}

__device__ inline float bred_sum(float v, float* sm, int tid) {
  sm[tid] = v; __syncthreads();
  for (int s = 128; s > 0; s >>= 1) { if (tid < s) sm[tid] += sm[tid + s]; __syncthreads(); }
  float r = sm[0]; __syncthreads();
  return r;
}

struct GP2 {
  const void* A; const void* B; const float* bias; void* C;
  const float* bias2;   // used for hh==1 when non-null
  u16* C2;              // optional secondary bf16 output (D2)
  int M, N, K, lda, ldb, ldc, Hdiv;
  long sAb, sAh, sBb, sBh, sCb, sCh;
  float scale;
};

// LDS tile: [128 rows][4 pieces of 16B]; physical piece = logical ^ ((row>>1)&3)
// swizzle spreads 8 consecutive lanes across 8 bank-quads -> conflict-free ds_read_b128

// ================= bf16 MFMA GEMM: C = epi(scale*A@B^T + bias) =================
// GL: stage both operands via global_load_lds (requires ABF&&BBF, M,N%128==0, K%32==0)
// 4 waves; each wave stages 16 rows/chunk x 2 chunks (rows wave*16.. and +64)
// D2: additionally store bf16 of final value to C2 (same index layout as C)
template<int EPI, bool ABF, bool BBF, bool ACC, bool CBF, bool GL, bool D2 = false>
__global__ __launch_bounds__(256) void mgemm_k(GP2 p) {
  __shared__ __align__(16) u16 As[4096];
  __shared__ __align__(16) u16 Bs[4096];
  int bb = blockIdx.z / p.Hdiv, hh = blockIdx.z % p.Hdiv;
  long aoff = (long)bb * p.sAb + (long)hh * p.sAh;
  long boff = (long)bb * p.sBb + (long)hh * p.sBh;
  long coff = (long)bb * p.sCb + (long)hh * p.sCh;
  int m0 = blockIdx.x * 128, n0 = blockIdx.y * 128;
  int tid = threadIdx.x, r = tid & 127, seg = tid >> 7;
  int lane = tid & 63, wave = tid >> 6;
  int wm = (wave >> 1) * 64, wn = (wave & 1) * 64;
  int l15 = lane & 15, quad = lane >> 4;
  int rs = (r >> 1) & 3;                       // write-side swizzle key (non-GL)
  int qs = (quad ^ ((l15 >> 1) & 3)) * 8;      // read-side swizzled piece offset
  f32x4 acc[4][4] = {};
  for (int k0 = 0; k0 < p.K; k0 += 32) {
    if constexpr (GL) {
      int lr = lane >> 2;
      int lc = (((lane & 3) ^ ((lane >> 3) & 3)) * 8);   // pre-swizzled global col
      const u16* Ab = (const u16*)p.A + aoff + (long)(m0 + wave * 16 + lr) * p.lda + k0 + lc;
      gld16(Ab,                    &As[wave * 512]);
      gld16(Ab + (long)64 * p.lda, &As[2048 + wave * 512]);
      const u16* Bb = (const u16*)p.B + boff + (long)(n0 + wave * 16 + lr) * p.ldb + k0 + lc;
      gld16(Bb,                    &Bs[wave * 512]);
      gld16(Bb + (long)64 * p.ldb, &Bs[2048 + wave * 512]);
    } else {
      bool kfull = (k0 + 32 <= p.K);
      int p0 = ((2 * seg) ^ rs) * 8;
      int p1 = ((2 * seg + 1) ^ rs) * 8;
      { // A stage
        int gm = m0 + r;
        if (ABF) {
          const u16* Ar = (const u16*)p.A + aoff + (long)gm * p.lda + k0 + seg * 16;
          if (kfull) {
            *(u32x4*)&As[r * 32 + p0] = *(const u32x4*)Ar;
            *(u32x4*)&As[r * 32 + p1] = *(const u32x4*)(Ar + 8);
          } else {
            for (int c = 0; c < 16; c++) {
              int kk = k0 + seg * 16 + c;
              int cc = seg * 16 + c;
              As[r * 32 + (((cc >> 3) ^ rs) << 3) + (cc & 7)] = (kk < p.K) ? Ar[c] : (u16)0;
            }
          }
        } else {
          const float* Ar = (const float*)p.A + aoff + (long)gm * p.lda + k0 + seg * 16;
          if (kfull) {
            float4 f0 = ((const float4*)Ar)[0];
            float4 f1 = ((const float4*)Ar)[1];
            float4 f2 = ((const float4*)Ar)[2];
            float4 f3 = ((const float4*)Ar)[3];
            *(u16x8*)&As[r * 32 + p0] = pack8(f0, f1);
            *(u16x8*)&As[r * 32 + p1] = pack8(f2, f3);
          } else {
            for (int c = 0; c < 16; c++) {
              int kk = k0 + seg * 16 + c;
              int cc = seg * 16 + c;
              As[r * 32 + (((cc >> 3) ^ rs) << 3) + (cc & 7)] = (kk < p.K) ? to_bf16(Ar[c]) : (u16)0;
            }
          }
        }
      }
      { // B stage (N x K)
        int gn = n0 + r;
        bool nv = gn < p.N;
        if (BBF) {
          const u16* Br = (const u16*)p.B + boff + (long)gn * p.ldb + k0 + seg * 16;
          if (nv && kfull) {
            *(u32x4*)&Bs[r * 32 + p0] = *(const u32x4*)Br;
            *(u32x4*)&Bs[r * 32 + p1] = *(const u32x4*)(Br + 8);
          } else {
            for (int c = 0; c < 16; c++) {
              int kk = k0 + seg * 16 + c;
              int cc = seg * 16 + c;
              Bs[r * 32 + (((cc >> 3) ^ rs) << 3) + (cc & 7)] = (nv && kk < p.K) ? Br[c] : (u16)0;
            }
          }
        } else {
          const float* Br = (const float*)p.B + boff + (long)gn * p.ldb + k0 + seg * 16;
          if (nv && kfull) {
            float4 f0 = ((const float4*)Br)[0];
            float4 f1 = ((const float4*)Br)[1];
            float4 f2 = ((const float4*)Br)[2];
            float4 f3 = ((const float4*)Br)[3];
            *(u16x8*)&Bs[r * 32 + p0] = pack8(f0, f1);
            *(u16x8*)&Bs[r * 32 + p1] = pack8(f2, f3);
          } else {
            for (int c = 0; c < 16; c++) {
              int kk = k0 + seg * 16 + c;
              int cc = seg * 16 + c;
              Bs[r * 32 + (((cc >> 3) ^ rs) << 3) + (cc & 7)] = (nv && kk < p.K) ? to_bf16(Br[c]) : (u16)0;
            }
          }
        }
      }
    }
    __syncthreads();
    s8v af[4], bfr[4];
#pragma unroll
    for (int i = 0; i < 4; i++) af[i]  = *(const s8v*)&As[(wm + i * 16 + l15) * 32 + qs];
#pragma unroll
    for (int j = 0; j < 4; j++) bfr[j] = *(const s8v*)&Bs[(wn + j * 16 + l15) * 32 + qs];
#pragma unroll
    for (int i = 0; i < 4; i++)
#pragma unroll
      for (int j = 0; j < 4; j++)
        acc[i][j] = __builtin_amdgcn_mfma_f32_16x16x32_bf16(af[i], bfr[j], acc[i][j], 0, 0, 0);
    __syncthreads();
  }
  const float* bp = (p.bias2 && (hh & 1)) ? p.bias2 : p.bias;
#pragma unroll
  for (int j = 0; j < 4; j++) {
    int col = n0 + wn + j * 16 + l15;
    if (col >= p.N) continue;
    float bv = bp ? bp[col] : 0.f;
#pragma unroll
    for (int i = 0; i < 4; i++) {
#pragma unroll
      for (int rr = 0; rr < 4; rr++) {
        int row = m0 + wm + i * 16 + quad * 4 + rr;
        float v = acc[i][j][rr] * p.scale + bv;
        if (EPI == 1) v = 0.5f * v * (1.f + erff(v * 0.70710678118654752f));
        if (EPI == 2) v = 1.f / (1.f + expf(-v));
        long ci = coff + (long)row * p.ldc + col;
        if (CBF) ((u16*)p.C)[ci] = to_bf16(v);
        else {
          float* Cp = (float*)p.C;
          if (ACC) v += Cp[ci];
          Cp[ci] = v;
          if (D2) p.C2[ci] = to_bf16(v);
        }
      }
    }
  }
}

// ================= conv1d k=3 pad=1, implicit im2col MFMA =================
// A staged via global_load_lds from bf16 x; OOB halo rows -> zero page (R9 form)
__global__ __launch_bounds__(256) void convm_k(const u16* __restrict__ xb,
    const u16* __restrict__ zp, const u16* __restrict__ wT,
    const float* __restrict__ bias, float* __restrict__ out) {
  __shared__ __align__(16) u16 As[4096];
  __shared__ __align__(16) u16 Bs[4096];
  int m0 = blockIdx.x * 128, n0 = blockIdx.y * 128;
  int b = m0 >> 8, tb = m0 & 255;
  int tid = threadIdx.x;
  int lane = tid & 63, wave = tid >> 6;
  int wm = (wave >> 1) * 64, wn = (wave & 1) * 64;
  int l15 = lane & 15, quad = lane >> 4;
  int lr = lane >> 2;
  int lc = (((lane & 3) ^ ((lane >> 3) & 3)) * 8);   // pre-swizzled global col
  int qs = (quad ^ ((l15 >> 1) & 3)) * 8;            // read-side swizzle
  int arow = wave * 16 + lr;
  f32x4 acc[4][4] = {};
  for (int k0 = 0; k0 < 3072; k0 += 32) {
    int kp = k0 >> 10, i0 = (k0 & 1023);
    int t2a = tb + arow + kp - 1;
    const u16* Aa = (t2a >= 0 && t2a < 256)
        ? xb + ((long)(b * 256 + t2a)) * 1024 + i0 + lc
        : zp + lc;
    gld16(Aa, &As[wave * 512]);
    int t2b = t2a + 64;
    const u16* Ab2 = (t2b >= 0 && t2b < 256)
        ? xb + ((long)(b * 256 + t2b)) * 1024 + i0 + lc
        : zp + lc;
    gld16(Ab2, &As[2048 + wave * 512]);
    const u16* Bb = wT + (long)(n0 + arow) * 3072 + k0 + lc;
    gld16(Bb,                   &Bs[wave * 512]);
    gld16(Bb + (long)64 * 3072, &Bs[2048 + wave * 512]);
    __syncthreads();
    s8v af[4], bfr[4];
#pragma unroll
    for (int i = 0; i < 4; i++) af[i]  = *(const s8v*)&As[(wm + i * 16 + l15) * 32 + qs];
#pragma unroll
    for (int j = 0; j < 4; j++) bfr[j] = *(const s8v*)&Bs[(wn + j * 16 + l15) * 32 + qs];
#pragma unroll
    for (int i = 0; i < 4; i++)
#pragma unroll
      for (int j = 0; j < 4; j++)
        acc[i][j] = __builtin_amdgcn_mfma_f32_16x16x32_bf16(af[i], bfr[j], acc[i][j], 0, 0, 0);
    __syncthreads();
  }
#pragma unroll
  for (int j = 0; j < 4; j++) {
    int col = n0 + wn + j * 16 + l15;
    float bv = bias[col];
#pragma unroll
    for (int i = 0; i < 4; i++)
#pragma unroll
      for (int rr = 0; rr < 4; rr++) {
        int row = m0 + wm + i * 16 + quad * 4 + rr;
        float v = acc[i][j][rr] + bv;
        out[(long)row * 512 + col] = v > 0.f ? v : 0.f;
      }
  }
}

// ================= transposes / converts =================
__global__ __launch_bounds__(256) void wtrans_k(const float* __restrict__ src,
    u16* __restrict__ dst, int R, int C) {
  __shared__ float t[32][33];
  int c0 = blockIdx.x * 32, r0 = blockIdx.y * 32;
  int tx = threadIdx.x & 31, ty = threadIdx.x >> 5;
  for (int rr = 0; rr < 32; rr += 8)
    t[ty + rr][tx] = src[(long)(r0 + ty + rr) * C + c0 + tx];
  __syncthreads();
  for (int rr = 0; rr < 32; rr += 8)
    dst[(long)(c0 + ty + rr) * R + r0 + tx] = to_bf16(t[tx][ty + rr]);
}

// 8 merged 512x512 transposes (z picks src / u16-offset into ws)
struct WT8 { const float* s[8]; long doff[8]; };
__global__ __launch_bounds__(256) void wt8_k(WT8 w, u16* __restrict__ base) {
  __shared__ float t[32][33];
  int z = blockIdx.z;
  const float* src = w.s[z];
  u16* dst = base + w.doff[z];
  int c0 = blockIdx.x * 32, r0 = blockIdx.y * 32;
  int tx = threadIdx.x & 31, ty = threadIdx.x >> 5;
  for (int rr = 0; rr < 32; rr += 8)
    t[ty + rr][tx] = src[(long)(r0 + ty + rr) * 512 + c0 + tx];
  __syncthreads();
  for (int rr = 0; rr < 32; rr += 8)
    dst[(long)(c0 + ty + rr) * 512 + r0 + tx] = to_bf16(t[tx][ty + rr]);
}

__global__ __launch_bounds__(256) void convw_t(const float* __restrict__ src, u16* __restrict__ dst) {
  int id = blockIdx.x * 256 + threadIdx.x;
  if (id >= 512 * 3072) return;
  int o = id / 3072, r2 = id % 3072;
  int kp = r2 >> 10, i = r2 & 1023;
  dst[id] = to_bf16(src[(long)o * 3072 + i * 3 + kp]);
}

// y=0: a_mem->amt ; y=1: n_mem->nmt  (512x64, K padded)
__global__ __launch_bounds__(256) void memtrans2_k(const float* __restrict__ a,
    const float* __restrict__ n, u16* __restrict__ amt, u16* __restrict__ nmt) {
  int id = blockIdx.x * 256 + threadIdx.x;
  if (id >= 512 * 64) return;
  const float* src = blockIdx.y ? n : a;
  u16* dst = blockIdx.y ? nmt : amt;
  int nn = id >> 6, k = id & 63;
  dst[id] = (k < 60) ? to_bf16(src[(long)k * 512 + nn]) : (u16)0;
}

// [2][128][512] bf16, rows 60..127 zero  (MEMORY PHASE only — overlaps scores)
__global__ __launch_bounds__(256) void membpad_k(const float* __restrict__ a,
    const float* __restrict__ n, u16* __restrict__ dst) {
  int id = blockIdx.x * 256 + threadIdx.x;   // < 131072
  int mat = id >> 16, r2 = id & 65535;
  int nr = r2 >> 9, k = r2 & 511;
  const float* s = mat ? n : a;
  dst[id] = (nr < 60) ? to_bf16(s[(long)nr * 512 + k]) : (u16)0;
}

__global__ __launch_bounds__(256) void vtrans_k(const u16* __restrict__ qkv, u16* __restrict__ vt) {
  __shared__ u16 t[32][33];
  int z = blockIdx.z;
  int b = z >> 2, h2 = z & 3;
  int t0 = blockIdx.x * 32, d0 = blockIdx.y * 32;
  int tx = threadIdx.x & 31, ty = threadIdx.x >> 5;
  const u16* src = qkv + (long)b * 393216 + 1024 + h2 * 128;
  for (int rr = 0; rr < 32; rr += 8)
    t[ty + rr][tx] = src[(long)(t0 + ty + rr) * 1536 + d0 + tx];
  __syncthreads();
  u16* dst = vt + (long)z * 32768;
  for (int rr = 0; rr < 32; rr += 8)
    dst[(long)(d0 + ty + rr) * 256 + t0 + tx] = t[tx][ty + rr];
}

// vectorized fp32 -> bf16 convert, 8 elems/thread (n % 8 == 0)
__global__ __launch_bounds__(256) void cvt_k(const float* __restrict__ src, u16* __restrict__ dst, long n) {
  long i = ((long)blockIdx.x * 256 + threadIdx.x) * 8;
  if (i >= n) return;
  float4 f0 = ((const float4*)(src + i))[0];
  float4 f1 = ((const float4*)(src + i))[1];
  *(u16x8*)(dst + i) = pack8(f0, f1);
}

__global__ void zpage_k(u16* __restrict__ z) { z[threadIdx.x] = 0; }

// ================= layernorm: wave-per-row, fp32 in -> bf16 out =================
__global__ __launch_bounds__(256) void ln_k(const float* __restrict__ in,
    const float* __restrict__ g, const float* __restrict__ b, u16* __restrict__ out) {
  int wave = threadIdx.x >> 6, lane = threadIdx.x & 63;
  long row = (long)blockIdx.x * 4 + wave;
  const float* r = in + row * 512 + lane * 8;
  float4 x0 = ((const float4*)r)[0];
  float4 x1 = ((const float4*)r)[1];
  float s = x0.x + x0.y + x0.z + x0.w + x1.x + x1.y + x1.z + x1.w;
  for (int off = 32; off; off >>= 1) s += __shfl_xor(s, off);
  float mean = s * (1.f / 512.f);
  float d[8] = {x0.x - mean, x0.y - mean, x0.z - mean, x0.w - mean,
                x1.x - mean, x1.y - mean, x1.z - mean, x1.w - mean};
  float q = 0.f;
#pragma unroll
  for (int i = 0; i < 8; i++) q += d[i] * d[i];
  for (int off = 32; off; off >>= 1) q += __shfl_xor(q, off);
  float inv = rsqrtf(q * (1.f / 512.f) + 1e-5f);
  const float4* gp = (const float4*)(g + lane * 8);
  const float4* bp = (const float4*)(b + lane * 8);
  float4 g0 = gp[0], g1 = gp[1], b0 = bp[0], b1 = bp[1];
  float gv[8] = {g0.x, g0.y, g0.z, g0.w, g1.x, g1.y, g1.z, g1.w};
  float bv[8] = {b0.x, b0.y, b0.z, b0.w, b1.x, b1.y, b1.z, b1.w};
  u16x8 o;
#pragma unroll
  for (int i = 0; i < 8; i++) o[i] = to_bf16(d[i] * inv * gv[i] + bv[i]);
  *(u16x8*)(out + row * 512 + lane * 8) = o;
}

// ========== softmax: wave-per-row (rows of 256), fp32 in -> bf16 out ==========
__global__ __launch_bounds__(256) void softmax_k(const float* __restrict__ s, u16* __restrict__ d) {
  int wave = threadIdx.x >> 6, lane = threadIdx.x & 63;
  long row = (long)blockIdx.x * 4 + wave;
  const float* r = s + row * 256 + lane * 4;
  float4 v = *(const float4*)r;
  float mx = fmaxf(fmaxf(v.x, v.y), fmaxf(v.z, v.w));
  for (int off = 32; off; off >>= 1) mx = fmaxf(mx, __shfl_xor(mx, off));
  v.x = expf(v.x - mx); v.y = expf(v.y - mx); v.z = expf(v.z - mx); v.w = expf(v.w - mx);
  float sum = v.x + v.y + v.z + v.w;
  for (int off = 32; off; off >>= 1) sum += __shfl_xor(sum, off);
  float is = 1.f / sum;
  u16x4 o;
  o[0] = to_bf16(v.x * is); o[1] = to_bf16(v.y * is);
  o[2] = to_bf16(v.z * is); o[3] = to_bf16(v.w * is);
  *(u16x4*)(d + row * 256 + lane * 4) = o;
}

// y picks source block (stride 491520) -> out block {0,24576,16384,8192}
__global__ __launch_bounds__(256) void top4_k(const float* __restrict__ att, float* __restrict__ out) {
  int y = blockIdx.y;
  int i = blockIdx.x * 256 + threadIdx.x;
  if (i >= HBT) return;
  const float* a = att + (long)y * 491520 + (long)i * 60;
  float t0 = -1e30f, t1 = -1e30f, t2 = -1e30f, t3 = -1e30f;
  for (int k = 0; k < 60; k++) {
    float v = a[k];
    if (v > t0)      { t3 = t2; t2 = t1; t1 = t0; t0 = v; }
    else if (v > t1) { t3 = t2; t2 = t1; t1 = v; }
    else if (v > t2) { t3 = t2; t2 = v; }
    else if (v > t3) { t3 = v; }
  }
  int ooff = (y == 0) ? 0 : (4 - y) * 8192;
  out[ooff + i] = (t0 + t1 + t2 + t3) * 0.25f;
}

// ========== top-17 over 256: block-parallel iterative argmax; y selects source row-block
__global__ __launch_bounds__(256) void topk17_k(const float* __restrict__ tatt, int* __restrict__ idx) {
  int b = blockIdx.x, y = blockIdx.y, tid = threadIdx.x;
  __shared__ float sv[256];
  __shared__ int si[256];
  float v = tatt[(long)y * 8192 + (long)b * 256 + tid];
  int* ob = idx + y * 544 + b * 17;
  for (int s = 0; s < 17; s++) {
    sv[tid] = v; si[tid] = tid;
    __syncthreads();
    for (int off = 128; off > 0; off >>= 1) {
      if (tid < off) {
        float v2 = sv[tid + off]; int i2 = si[tid + off];
        if (v2 > sv[tid] || (v2 == sv[tid] && i2 < si[tid])) { sv[tid] = v2; si[tid] = i2; }
      }
      __syncthreads();
    }
    int win = si[0];
    if (tid == 0) ob[s] = win;
    if (tid == win) v = -1e30f;
    __syncthreads();
  }
}

__device__ inline void gmean_body(const float* feats, const int* idx, float* out, int b, int tid) {
  float s0 = 0.f, s1 = 0.f;
  for (int j = 0; j < 17; j++) {
    int t = idx[b * 17 + j];
    const float* r = feats + ((long)b * 256 + t) * 512;
    s0 += r[tid]; s1 += r[tid + 256];
  }
  out[(long)b * 512 + tid]       = s0 * (1.f / 17.f);
  out[(long)b * 512 + tid + 256] = s1 * (1.f / 17.f);
}

// y=0: (Ax, idxA)->NEG ; y=1: (Nx, idxN)->ANC ; y=2: (Ax, idxP)->POS
__global__ __launch_bounds__(256) void gmean3_k(const float* __restrict__ Ax,
    const float* __restrict__ Nx, const int* __restrict__ idx0, float* __restrict__ ob) {
  int b = blockIdx.x, y = blockIdx.y, tid = threadIdx.x;
  const float* feats = (y == 1) ? Nx : Ax;
  const int* idx = idx0 + y * 544;
  float* out = ob + (long)((y + 2) % 3) * 16384;
  gmean_body(feats, idx, out, b, tid);
}

// y=0: (f0=nnew, idxN)->ANEW ; y=1: (f1=R0, idxA)->NNEG
__global__ __launch_bounds__(256) void gmean2_k(const float* __restrict__ f0,
    const float* __restrict__ f1, const int* __restrict__ idx0, float* __restrict__ ob) {
  int b = blockIdx.x, y = blockIdx.y, tid = threadIdx.x;
  const float* feats = y ? f1 : f0;
  const int* idx = idx0 + (y == 0 ? 544 : 0);
  float* out = ob + (long)y * 16384;
  gmean_body(feats, idx, out, b, tid);
}

// vae: nnew may alias mu (elementwise read-before-write)
__global__ __launch_bounds__(256) void vae_k(const float* __restrict__ mu,
    const float* __restrict__ var, const float* __restrict__ eps,
    float* __restrict__ nnew, float* __restrict__ accum) {
  constexpr long N4 = HHf / 4;
  long stride = (long)gridDim.x * 256;
  float kle = 0.f;
  for (long i = (long)blockIdx.x * 256 + threadIdx.x; i < N4; i += stride) {
    float4 m4 = ((const float4*)mu)[i];
    float4 v4 = ((const float4*)var)[i];
    float4 e4 = ((const float4*)eps)[i];
    float4 o;
    float ev;
    ev = expf(v4.x); o.x = m4.x + e4.x * sqrtf(ev); kle += 1.f + v4.x - m4.x * m4.x - ev;
    ev = expf(v4.y); o.y = m4.y + e4.y * sqrtf(ev); kle += 1.f + v4.y - m4.y * m4.y - ev;
    ev = expf(v4.z); o.z = m4.z + e4.z * sqrtf(ev); kle += 1.f + v4.z - m4.z * m4.z - ev;
    ev = expf(v4.w); o.w = m4.w + e4.w * sqrtf(ev); kle += 1.f + v4.w - m4.w * m4.w - ev;
    ((float4*)nnew)[i] = o;
  }
  __shared__ float sm[256];
  float s = bred_sum(kle, sm, threadIdx.x);
  if (threadIdx.x == 0) atomicAdd(accum + 0, s);
}

__global__ __launch_bounds__(256) void tripcos_k(const float* __restrict__ anc,
    const float* __restrict__ pos, const float* __restrict__ neg, float* __restrict__ accum) {
  int b = blockIdx.x, tid = threadIdx.x;
  const float *a = anc + (long)b * 512, *p = pos + (long)b * 512, *n = neg + (long)b * 512;
  float a0 = a[tid], a1 = a[tid + 256], p0 = p[tid], p1 = p[tid + 256], n0 = n[tid], n1 = n[tid + 256];
  __shared__ float sm[256];
  float sa  = bred_sum(a0 * a0 + a1 * a1, sm, tid);
  float sp  = bred_sum(p0 * p0 + p1 * p1, sm, tid);
  float sn  = bred_sum(n0 * n0 + n1 * n1, sm, tid);
  float dot = bred_sum(a0 * n0 + a1 * n1, sm, tid);
  float na = sqrtf(sa), np_ = sqrtf(sp), nn = sqrtf(sn);
  float ina = 1.f / na, inp = 1.f / np_, inn = 1.f / nn;
  float d0 = a0 * ina - p0 * inp + 1e-6f, d1 = a1 * ina - p1 * inp + 1e-6f;
  float e0 = a0 * ina - n0 * inn + 1e-6f, e1 = a1 * ina - n1 * inn + 1e-6f;
  float dp2 = bred_sum(d0 * d0 + d1 * d1, sm, tid);
  float dn2 = bred_sum(e0 * e0 + e1 * e1, sm, tid);
  if (tid == 0) {
    float dp = sqrtf(dp2), dn = sqrtf(dn2);
    float t = dp - dn + 1.f;
    atomicAdd(accum + 1, t > 0.f ? t : 0.f);
    float c = 1.f - dot / (fmaxf(na, 1e-6f) * fmaxf(nn, 1e-6f));
    atomicAdd(accum + 2, c);
  }
}

__global__ __launch_bounds__(256) void dist_k(const float* __restrict__ anew,
    const float* __restrict__ nneg, float* __restrict__ accum) {
  int b = blockIdx.x, tid = threadIdx.x;
  const float *a = anew + (long)b * 512, *n = nneg + (long)b * 512;
  float a0 = a[tid], a1 = a[tid + 256], n0 = n[tid], n1 = n[tid + 256];
  __shared__ float sm[256];
  float sa = bred_sum(a0 * a0 + a1 * a1, sm, tid);
  float sn = bred_sum(n0 * n0 + n1 * n1, sm, tid);
  if (tid == 0) {
    float v = 100.f - sqrtf(sn) + sqrtf(sa);
    atomicAdd(accum + 3, v > 0.f ? v : 0.f);
  }
}

// float4 version: 4 elems/thread; grid 8192
__global__ __launch_bounds__(256) void xout_k(const float* __restrict__ emb,
    const float* __restrict__ nnew, const float* __restrict__ anm,
    const float* __restrict__ anew, const float* __restrict__ nam,
    float* __restrict__ xout) {
  long q = (long)blockIdx.x * 256 + threadIdx.x;   // float4 index, < 2097152
  long i = q * 4;
  long row = i >> 9;
  int d = (int)(i & 511);
  long o = row * 1024 + d;
  *(float4*)(xout + o) = ((const float4*)emb)[q];
  float4 v;
  if (i < HHf) {
    float4 a = ((const float4*)nnew)[q];
    float4 b = ((const float4*)anm)[q];
    v.x = a.x + b.x; v.y = a.y + b.y; v.z = a.z + b.z; v.w = a.w + b.w;
  } else {
    long q2 = q - HHf / 4;
    float4 a = ((const float4*)anew)[q2];
    float4 b = ((const float4*)nam)[q2];
    v.x = a.x + b.x; v.y = a.y + b.y; v.z = a.z + b.z; v.w = a.w + b.w;
  }
  *(float4*)(xout + o + 512) = v;
}

__global__ __launch_bounds__(256) void vfeat_k(const float* __restrict__ emb, float* __restrict__ vf) {
  __shared__ float tile[32][33];
  int b = blockIdx.z;
  int t0 = blockIdx.x * 32, d0 = blockIdx.y * 32;
  int tx = threadIdx.x & 31, ty = threadIdx.x >> 5;
  for (int r = 0; r < 32; r += 8)
    tile[ty + r][tx] = emb[((long)b * 256 + t0 + ty + r) * 512 + d0 + tx];
  __syncthreads();
  for (int r = 0; r < 32; r += 8)
    vf[((long)b * 512 + d0 + ty + r) * 256 + t0 + tx] = tile[tx][ty + r];
}

__global__ void init_k(float* accum) {
  accum[0] = 0.f; accum[1] = 0.f; accum[2] = 0.f; accum[3] = 0.f;
}

__global__ void fin_k(const float* __restrict__ accum, float* __restrict__ out) {
  out[0] = accum[1] * (1.f / 32.f);
  out[1] = -0.5f * accum[0] * (1.f / 16384.f);
  out[2] = accum[3] * (1.f / 32.f);
  out[OO_COS] = accum[2] * (1.f / 32.f);
}

static inline GP2 mk(const void* A, const void* B, const float* bias, void* C,
                     int M, int N, int K, int lda, int ldb, int ldc,
                     float scale = 1.f, int Hdiv = 1,
                     long sAb = 0, long sAh = 0, long sBb = 0, long sBh = 0,
                     long sCb = 0, long sCh = 0, const float* bias2 = nullptr,
                     u16* C2 = nullptr) {
  GP2 p; p.A = A; p.B = B; p.bias = bias; p.C = C; p.bias2 = bias2; p.C2 = C2;
  p.M = M; p.N = N; p.K = K; p.lda = lda; p.ldb = ldb; p.ldc = ldc;
  p.Hdiv = Hdiv; p.sAb = sAb; p.sAh = sAh; p.sBb = sBb; p.sBh = sBh;
  p.sCb = sCb; p.sCh = sCh; p.scale = scale;
  return p;
}

} // namespace

extern "C" void kernel_launch(void* const* d_in, const int* in_sizes, int n_in,
                              void* d_out, int out_size, void* d_ws, size_t ws_size,
                              hipStream_t stream) {
  const float* x      = (const float*)d_in[0];
  const float* epsi   = (const float*)d_in[1];
  const float* conv_w = (const float*)d_in[2];
  const float* conv_b = (const float*)d_in[3];
  const float* ln1_g  = (const float*)d_in[4];
  const float* ln1_b  = (const float*)d_in[5];
  const float* qkv_w  = (const float*)d_in[6];
  const float* out_w  = (const float*)d_in[7];
  const float* out_b  = (const float*)d_in[8];
  const float* ln2_g  = (const float*)d_in[9];
  const float* ln2_b  = (const float*)d_in[10];
  const float* ff1_w  = (const float*)d_in[11];
  const float* ff1_b  = (const float*)d_in[12];
  const float* ff2_w  = (const float*)d_in[13];
  const float* ff2_b  = (const float*)d_in[14];
  const float* a_mem  = (const float*)d_in[15];
  const float* n_mem  = (const float*)d_in[16];
  const float* mu_w   = (const float*)d_in[17];
  const float* mu_b   = (const float*)d_in[18];
  const float* var_w  = (const float*)d_in[19];
  const float* var_b  = (const float*)d_in[20];
  float* out = (float*)d_out;
  float* ws  = (float*)d_ws;

  const float ATTSCALE = 0.08838834764831845f;
  const float SIGSCALE = 0.04419417382415922f;

  float* h   = ws + F_H;
  u16* lnb   = (u16*)(ws + F_LNB);
  u16* qkvb  = (u16*)(ws + F_QKV);
  u16* vtb   = (u16*)(ws + F_VT);
  float* scf = ws + F_SC;
  u16* scb   = qkvb;                  // bf16 P (softmax out) reuses qkv region
  u16* wqkvT = (u16*)(ws + W_QKV);
  u16* woutT = (u16*)(ws + W_OUT);
  u16* wff1T = (u16*)(ws + W_FF1);
  u16* wff2T = (u16*)(ws + W_FF2);
  u16* wmuT  = (u16*)(ws + W_MU);
  u16* wconvT= (u16*)(ws + W_CONV);
  u16* amtT  = (u16*)(ws + W_AMT);
  u16* nmtT  = (u16*)(ws + W_NMT);
  u16* membT = (u16*)(ws + W_MEMB);   // [2][128][512] bf16 zero-padded (memory phase)
  u16* zpage = (u16*)(ws + Z_PG);
  u16* xb    = (u16*)(ws + F_QKV);    // x in bf16 (conv phase only)

  // ---- weight transposes ----
  wtrans_k<<<dim3(48, 16), 256, 0, stream>>>(qkv_w,          wqkvT,          512, 1536);
  wtrans_k<<<dim3(48, 16), 256, 0, stream>>>(qkv_w + 786432, wqkvT + 786432, 512, 1536);
  {
    WT8 w;
    w.s[0] = out_w;          w.doff[0] = 2 * W_OUT;
    w.s[1] = out_w + 262144; w.doff[1] = 2 * W_OUT + 262144;
    w.s[2] = ff1_w;          w.doff[2] = 2 * W_FF1;
    w.s[3] = ff1_w + 262144; w.doff[3] = 2 * W_FF1 + 262144;
    w.s[4] = ff2_w;          w.doff[4] = 2 * W_FF2;
    w.s[5] = ff2_w + 262144; w.doff[5] = 2 * W_FF2 + 262144;
    w.s[6] = mu_w;           w.doff[6] = 2 * W_MU;
    w.s[7] = var_w;          w.doff[7] = 2 * W_VAR;
    wt8_k<<<dim3(16, 16, 8), 256, 0, stream>>>(w, (u16*)ws);
  }
  convw_t<<<6144, 256, 0, stream>>>(conv_w, wconvT);
  memtrans2_k<<<dim3(128, 2), 256, 0, stream>>>(a_mem, n_mem, amtT, nmtT);

  // ---- conv + relu -> h (A via bf16 x + global_load_lds) ----
  cvt_k<<<8192, 256, 0, stream>>>(x, xb, 16777216);
  zpage_k<<<1, 256, 0, stream>>>(zpage);
  convm_k<<<dim3(128, 4), 256, 0, stream>>>(xb, zpage, wconvT, conv_b, h);

  // ---- transformer ----
  u16* hb = lnb;
  for (int i = 0; i < 2; i++) {
    ln_k<<<4096, 256, 0, stream>>>(h, ln1_g + i * 512, ln1_b + i * 512, lnb);
    {
      GP2 p = mk(lnb, wqkvT + (long)i * 786432, nullptr, qkvb, 16384, 1536, 512, 512, 512, 1536);
      mgemm_k<0, true, true, false, true, true><<<dim3(128, 12, 1), 256, 0, stream>>>(p);
    }
    vtrans_k<<<dim3(8, 4, 256), 256, 0, stream>>>(qkvb, vtb);
    {
      GP2 p = mk(qkvb, qkvb + 512, nullptr, scf, 256, 256, 128, 1536, 1536, 256,
                 ATTSCALE, 4, 393216, 128, 393216, 128, 262144, 65536);
      mgemm_k<0, true, true, false, false, true><<<dim3(2, 2, 256), 256, 0, stream>>>(p);
    }
    // softmax: fp32 scores -> bf16 P (overwrites dead Q/K rows; V already in vtb)
    softmax_k<<<16384, 256, 0, stream>>>(scf, scb);
    {
      GP2 p = mk(scb, vtb, nullptr, lnb, 256, 128, 256, 256, 256, 512,
                 1.f, 4, 262144, 65536, 131072, 32768, 131072, 128);
      mgemm_k<0, true, true, false, true, true><<<dim3(2, 1, 256), 256, 0, stream>>>(p);
    }
    {
      GP2 p = mk(lnb, woutT + (long)i * 262144, out_b + i * 512, h, 16384, 512, 512, 512, 512, 512);
      mgemm_k<0, true, true, true, false, true><<<dim3(128, 4, 1), 256, 0, stream>>>(p);
    }
    ln_k<<<4096, 256, 0, stream>>>(h, ln2_g + i * 512, ln2_b + i * 512, lnb);
    {
      GP2 p = mk(lnb, wff1T + (long)i * 262144, ff1_b + i * 512, qkvb, 16384, 512, 512, 512, 512, 512);
      mgemm_k<1, true, true, false, true, true><<<dim3(128, 4, 1), 256, 0, stream>>>(p);
    }
    if (i == 0) {
      GP2 p = mk(qkvb, wff2T, ff2_b, h, 16384, 512, 512, 512, 512, 512);
      mgemm_k<0, true, true, true, false, true><<<dim3(128, 4, 1), 256, 0, stream>>>(p);
    } else {
      // layer 1 ff2: fused dual write — fp32 h (residual acc) + bf16 hb
      GP2 p = mk(qkvb, wff2T + 262144, ff2_b + 512, h, 16384, 512, 512, 512, 512, 512,
                 1.f, 1, 0, 0, 0, 0, 0, 0, nullptr, hb);
      mgemm_k<0, true, true, true, false, true, true><<<dim3(128, 4, 1), 256, 0, stream>>>(p);
    }
  }

  // ---- memory phase (hb already written by fused ff2 epilogue) ----
  membpad_k<<<512, 256, 0, stream>>>(a_mem, n_mem, membT);
  const float* Nx = h;
  const float* Ax = h + HHf;
  const u16* Axb = hb + HHf;
  float* attA  = ws + F_ATT;
  float* attN  = ws + F_ATT + 1474560;

  // 4 att GEMMs, one GL launch: bb picks Ax/Nx, hh picks a_mem/n_mem (padded B)
  {
    GP2 p = mk(Axb, membT, nullptr, attA, HBT, 60, 512, 512, 512, 60, SIGSCALE,
               2, -(long)HHf, 0, 0, 65536, 983040, 491520);
    mgemm_k<2, true, true, false, false, true><<<dim3(64, 1, 4), 256, 0, stream>>>(p);
  }

  // merged 4-way top4
  top4_k<<<dim3(32, 4), 256, 0, stream>>>(attA, out + OO_AATT);

  // 4 aug GEMMs in one launch; C order: augA, augNA, augAN, augN
  u16* augb = (u16*)(ws + F_AUG);
  u16* augA  = augb;
  u16* augN  = augb + 3 * HHf;
  {
    GP2 p = mk(attA, amtT, nullptr, augA, HBT, 512, 60, 60, 64, 512, 1.f,
               2, 983040, 491520, 0, 32768, 2 * HHf, HHf);
    mgemm_k<0, false, true, false, true, false><<<dim3(64, 4, 4), 256, 0, stream>>>(p);
  }

  float* accum = ws + O_ACC;
  int* idxA = (int*)(ws + O_IDX);
  init_k<<<1, 1, 0, stream>>>(accum);

  topk17_k<<<dim3(32, 3), 256, 0, stream>>>(out + OO_AATT, idxA);
  gmean3_k<<<dim3(32, 3), 256, 0, stream>>>(Ax, Nx, idxA, ws + O_ANC);
  tripcos_k<<<32, 256, 0, stream>>>(ws + O_ANC, ws + O_POS, ws + O_NEG, accum);

  // round1: augN @ {mu,var} in one launch
  {
    GP2 p = mk(augN, wmuT, mu_b, ws + F_MU, HBT, 512, 512, 512, 512, 512, 1.f,
               2, 0, 0, 0, 262144, 0, 4194304, var_b);
    mgemm_k<0, true, true, false, false, true><<<dim3(64, 4, 2), 256, 0, stream>>>(p);
  }
  vae_k<<<512, 256, 0, stream>>>(ws + F_MU, ws + F_VAR, epsi, ws + F_MU, accum);

  // round2: {augA, augNA, augAN} @ mu -> {R0=anew, R1=nam, R2=anm}
  {
    GP2 p = mk(augA, wmuT, mu_b, ws + F_R0, HBT, 512, 512, 512, 512, 512, 1.f,
               1, HHf, 0, 0, 0, 4194304, 0);
    mgemm_k<0, true, true, false, false, true><<<dim3(64, 4, 3), 256, 0, stream>>>(p);
  }

  gmean2_k<<<dim3(32, 2), 256, 0, stream>>>(ws + F_MU, ws + F_R0, idxA, ws + O_ANEW);
  dist_k<<<32, 256, 0, stream>>>(ws + O_ANEW, ws + O_NNEG, accum);

  xout_k<<<8192, 256, 0, stream>>>(h, ws + F_MU, ws + F_R2, ws + F_R0, ws + F_R1,
                                   out + OO_XOUT);
  vfeat_k<<<dim3(8, 16, 64), 256, 0, stream>>>(h, out + OO_VFEAT);
  fin_k<<<1, 1, 0, stream>>>(accum, out);
}

// Round 14
// 956.548 us; speedup vs baseline: 1.1549x; 1.1549x over previous
//
#include <hip/hip_runtime.h>
#include <math.h>

namespace {

typedef unsigned short u16;
typedef __attribute__((ext_vector_type(8))) short s8v;
typedef __attribute__((ext_vector_type(8))) unsigned short u16x8;
typedef __attribute__((ext_vector_type(4))) unsigned short u16x4;
typedef __attribute__((ext_vector_type(4))) float f32x4;
typedef __attribute__((ext_vector_type(4))) unsigned int u32x4;

constexpr int HBT = 8192;            // 32*256
constexpr long HHf = 4194304;        // 8192*512

// ---- workspace offsets (float units) ----
constexpr long F_H    = 0;           // h / x_emb fp32 (8388608)
constexpr long F_LNB  = 8388608;     // ln / o / hbf bf16
constexpr long F_QKV  = 12582912;    // qkv bf16; xb during conv; P (bf16) after softmax; ff1 out
constexpr long F_VT   = 25165824;    // v^T bf16
constexpr long F_SC   = 29360128;    // scores fp32 (16777216) -> region ends 46137344
// phase M (QKV/VT/SC regions dead):
constexpr long F_ATT  = 12582912;    // 4 x 491520 fp32: attA, attNA, attAN, attN
constexpr long F_AUG  = 14548992;    // 4 x 4194304 u16: augA, augNA, augAN, augN
constexpr long F_MU   = 22937600;    // fp32 (round1 mu out; vae overwrites with nnew)
constexpr long F_VAR  = 27131904;    // round1 var out
constexpr long F_R0   = 31326208;    // round2: A_aug_new
constexpr long F_R1   = 35520512;    // round2: N_Aaug_m (nam)
constexpr long F_R2   = 39714816;    // round2: A_Naug_m (anm)
// membT overlaps the (dead-by-then) scores region; filled in MEMORY PHASE only.
constexpr long W_MEMB = 43909120;    // bf16 [2][128][512] zero-padded (131072 u16 = 65536 fl)
constexpr long Z_PG   = 43974656;    // zero page (256 u16) — conv phase only
// transposed weights (bf16), live whole launch:
constexpr long W_QKV  = 46137344;    // 2 x 786432 u16
constexpr long W_OUT  = 46923776;    // 2 x 262144 u16
constexpr long W_FF1  = 47185920;
constexpr long W_FF2  = 47448064;
constexpr long W_MU   = 47710208;    // 262144 u16
constexpr long W_VAR  = 47841280;
constexpr long W_CONV = 47972352;    // 1572864 u16
constexpr long W_AMT  = 48758784;    // 32768 u16 (512x64 padded)
constexpr long W_NMT  = 48775168;
constexpr long O_ANC  = 48791552;
constexpr long O_POS  = O_ANC + 16384;
constexpr long O_NEG  = O_POS + 16384;
constexpr long O_ANEW = O_NEG + 16384;
constexpr long O_NNEG = O_ANEW + 16384;
constexpr long O_IDX  = O_NNEG + 16384;   // 3*544 ints
constexpr long O_ACC  = O_IDX + 1632;     // 4 floats

// ---- output offsets ----
constexpr long OO_AATT  = 3;
constexpr long OO_NATT  = 3 + 8192;
constexpr long OO_ANATT = 3 + 16384;
constexpr long OO_NAATT = 3 + 24576;
constexpr long OO_COS   = 32771;
constexpr long OO_XOUT  = 32772;
constexpr long OO_VFEAT = 32772L + 16777216L;

__device__ inline u16 to_bf16(float f) {
  union { float f; unsigned u; } x; x.f = f;
  unsigned r = x.u + 0x7fffu + ((x.u >> 16) & 1u);
  return (u16)(r >> 16);
}
__device__ inline u16x8 pack8(float4 a, float4 b) {
  u16x8 r;
  r[0]=to_bf16(a.x); r[1]=to_bf16(a.y); r[2]=to_bf16(a.z); r[3]=to_bf16(a.w);
  r[4]=to_bf16(b.x); r[5]=to_bf16(b.y); r[6]=to_bf16(b.z); r[7]=to_bf16(b.w);
  return r;
}

// async global->LDS, 16B per lane; LDS dest = wave-uniform base + lane*16
typedef __attribute__((address_space(1))) void gvoid;
typedef __attribute__((address_space(3))) void lvoid;
__device__ inline void gld16(const u16* g, u16* l) {
  __builtin_amdgcn_global_load_lds((gvoid*)g, (lvoid*)l, 16, 0, 0);
}

__device__ inline float bred_sum(float v, float* sm, int tid) {
  sm[tid] = v; __syncthreads();
  for (int s = 128; s > 0; s >>= 1) { if (tid < s) sm[tid] += sm[tid + s]; __syncthreads(); }
  float r = sm[0]; __syncthreads();
  return r;
}

struct GP2 {
  const void* A; const void* B; const float* bias; void* C;
  const float* bias2;   // used for hh==1 when non-null
  u16* C2;              // optional secondary bf16 output (D2)
  int M, N, K, lda, ldb, ldc, Hdiv;
  long sAb, sAh, sBb, sBh, sCb, sCh;
  float scale;
};

// LDS tile: [128 rows][4 pieces of 16B]; physical piece = logical ^ ((row>>1)&3)
// swizzle spreads 8 consecutive lanes across 8 bank-quads -> conflict-free ds_read_b128

// ================= bf16 MFMA GEMM: C = epi(scale*A@B^T + bias) =================
// GL: stage both operands via global_load_lds (requires ABF&&BBF, M,N%128==0, K%32==0)
// 4 waves; each wave stages 16 rows/chunk x 2 chunks (rows wave*16.. and +64)
// D2: additionally store bf16 of final value to C2 (same index layout as C)
template<int EPI, bool ABF, bool BBF, bool ACC, bool CBF, bool GL, bool D2 = false>
__global__ __launch_bounds__(256) void mgemm_k(GP2 p) {
  __shared__ __align__(16) u16 As[4096];
  __shared__ __align__(16) u16 Bs[4096];
  int bb = blockIdx.z / p.Hdiv, hh = blockIdx.z % p.Hdiv;
  long aoff = (long)bb * p.sAb + (long)hh * p.sAh;
  long boff = (long)bb * p.sBb + (long)hh * p.sBh;
  long coff = (long)bb * p.sCb + (long)hh * p.sCh;
  int m0 = blockIdx.x * 128, n0 = blockIdx.y * 128;
  int tid = threadIdx.x, r = tid & 127, seg = tid >> 7;
  int lane = tid & 63, wave = tid >> 6;
  int wm = (wave >> 1) * 64, wn = (wave & 1) * 64;
  int l15 = lane & 15, quad = lane >> 4;
  int rs = (r >> 1) & 3;                       // write-side swizzle key (non-GL)
  int qs = (quad ^ ((l15 >> 1) & 3)) * 8;      // read-side swizzled piece offset
  f32x4 acc[4][4] = {};
  for (int k0 = 0; k0 < p.K; k0 += 32) {
    if constexpr (GL) {
      int lr = lane >> 2;
      int lc = (((lane & 3) ^ ((lane >> 3) & 3)) * 8);   // pre-swizzled global col
      const u16* Ab = (const u16*)p.A + aoff + (long)(m0 + wave * 16 + lr) * p.lda + k0 + lc;
      gld16(Ab,                    &As[wave * 512]);
      gld16(Ab + (long)64 * p.lda, &As[2048 + wave * 512]);
      const u16* Bb = (const u16*)p.B + boff + (long)(n0 + wave * 16 + lr) * p.ldb + k0 + lc;
      gld16(Bb,                    &Bs[wave * 512]);
      gld16(Bb + (long)64 * p.ldb, &Bs[2048 + wave * 512]);
    } else {
      bool kfull = (k0 + 32 <= p.K);
      int p0 = ((2 * seg) ^ rs) * 8;
      int p1 = ((2 * seg + 1) ^ rs) * 8;
      { // A stage
        int gm = m0 + r;
        if (ABF) {
          const u16* Ar = (const u16*)p.A + aoff + (long)gm * p.lda + k0 + seg * 16;
          if (kfull) {
            *(u32x4*)&As[r * 32 + p0] = *(const u32x4*)Ar;
            *(u32x4*)&As[r * 32 + p1] = *(const u32x4*)(Ar + 8);
          } else {
            for (int c = 0; c < 16; c++) {
              int kk = k0 + seg * 16 + c;
              int cc = seg * 16 + c;
              As[r * 32 + (((cc >> 3) ^ rs) << 3) + (cc & 7)] = (kk < p.K) ? Ar[c] : (u16)0;
            }
          }
        } else {
          const float* Ar = (const float*)p.A + aoff + (long)gm * p.lda + k0 + seg * 16;
          if (kfull) {
            float4 f0 = ((const float4*)Ar)[0];
            float4 f1 = ((const float4*)Ar)[1];
            float4 f2 = ((const float4*)Ar)[2];
            float4 f3 = ((const float4*)Ar)[3];
            *(u16x8*)&As[r * 32 + p0] = pack8(f0, f1);
            *(u16x8*)&As[r * 32 + p1] = pack8(f2, f3);
          } else {
            for (int c = 0; c < 16; c++) {
              int kk = k0 + seg * 16 + c;
              int cc = seg * 16 + c;
              As[r * 32 + (((cc >> 3) ^ rs) << 3) + (cc & 7)] = (kk < p.K) ? to_bf16(Ar[c]) : (u16)0;
            }
          }
        }
      }
      { // B stage (N x K)
        int gn = n0 + r;
        bool nv = gn < p.N;
        if (BBF) {
          const u16* Br = (const u16*)p.B + boff + (long)gn * p.ldb + k0 + seg * 16;
          if (nv && kfull) {
            *(u32x4*)&Bs[r * 32 + p0] = *(const u32x4*)Br;
            *(u32x4*)&Bs[r * 32 + p1] = *(const u32x4*)(Br + 8);
          } else {
            for (int c = 0; c < 16; c++) {
              int kk = k0 + seg * 16 + c;
              int cc = seg * 16 + c;
              Bs[r * 32 + (((cc >> 3) ^ rs) << 3) + (cc & 7)] = (nv && kk < p.K) ? Br[c] : (u16)0;
            }
          }
        } else {
          const float* Br = (const float*)p.B + boff + (long)gn * p.ldb + k0 + seg * 16;
          if (nv && kfull) {
            float4 f0 = ((const float4*)Br)[0];
            float4 f1 = ((const float4*)Br)[1];
            float4 f2 = ((const float4*)Br)[2];
            float4 f3 = ((const float4*)Br)[3];
            *(u16x8*)&Bs[r * 32 + p0] = pack8(f0, f1);
            *(u16x8*)&Bs[r * 32 + p1] = pack8(f2, f3);
          } else {
            for (int c = 0; c < 16; c++) {
              int kk = k0 + seg * 16 + c;
              int cc = seg * 16 + c;
              Bs[r * 32 + (((cc >> 3) ^ rs) << 3) + (cc & 7)] = (nv && kk < p.K) ? to_bf16(Br[c]) : (u16)0;
            }
          }
        }
      }
    }
    __syncthreads();
    s8v af[4], bfr[4];
#pragma unroll
    for (int i = 0; i < 4; i++) af[i]  = *(const s8v*)&As[(wm + i * 16 + l15) * 32 + qs];
#pragma unroll
    for (int j = 0; j < 4; j++) bfr[j] = *(const s8v*)&Bs[(wn + j * 16 + l15) * 32 + qs];
#pragma unroll
    for (int i = 0; i < 4; i++)
#pragma unroll
      for (int j = 0; j < 4; j++)
        acc[i][j] = __builtin_amdgcn_mfma_f32_16x16x32_bf16(af[i], bfr[j], acc[i][j], 0, 0, 0);
    __syncthreads();
  }
  const float* bp = (p.bias2 && (hh & 1)) ? p.bias2 : p.bias;
#pragma unroll
  for (int j = 0; j < 4; j++) {
    int col = n0 + wn + j * 16 + l15;
    if (col >= p.N) continue;
    float bv = bp ? bp[col] : 0.f;
#pragma unroll
    for (int i = 0; i < 4; i++) {
#pragma unroll
      for (int rr = 0; rr < 4; rr++) {
        int row = m0 + wm + i * 16 + quad * 4 + rr;
        float v = acc[i][j][rr] * p.scale + bv;
        if (EPI == 1) v = 0.5f * v * (1.f + erff(v * 0.70710678118654752f));
        if (EPI == 2) v = 1.f / (1.f + expf(-v));
        long ci = coff + (long)row * p.ldc + col;
        if (CBF) ((u16*)p.C)[ci] = to_bf16(v);
        else {
          float* Cp = (float*)p.C;
          if (ACC) v += Cp[ci];
          Cp[ci] = v;
          if (D2) p.C2[ci] = to_bf16(v);
        }
      }
    }
  }
}

// ================= conv1d k=3 pad=1, implicit im2col MFMA =================
// A staged via global_load_lds from bf16 x; OOB halo rows -> zero page (R9 form)
__global__ __launch_bounds__(256) void convm_k(const u16* __restrict__ xb,
    const u16* __restrict__ zp, const u16* __restrict__ wT,
    const float* __restrict__ bias, float* __restrict__ out) {
  __shared__ __align__(16) u16 As[4096];
  __shared__ __align__(16) u16 Bs[4096];
  int m0 = blockIdx.x * 128, n0 = blockIdx.y * 128;
  int b = m0 >> 8, tb = m0 & 255;
  int tid = threadIdx.x;
  int lane = tid & 63, wave = tid >> 6;
  int wm = (wave >> 1) * 64, wn = (wave & 1) * 64;
  int l15 = lane & 15, quad = lane >> 4;
  int lr = lane >> 2;
  int lc = (((lane & 3) ^ ((lane >> 3) & 3)) * 8);   // pre-swizzled global col
  int qs = (quad ^ ((l15 >> 1) & 3)) * 8;            // read-side swizzle
  int arow = wave * 16 + lr;
  f32x4 acc[4][4] = {};
  for (int k0 = 0; k0 < 3072; k0 += 32) {
    int kp = k0 >> 10, i0 = (k0 & 1023);
    int t2a = tb + arow + kp - 1;
    const u16* Aa = (t2a >= 0 && t2a < 256)
        ? xb + ((long)(b * 256 + t2a)) * 1024 + i0 + lc
        : zp + lc;
    gld16(Aa, &As[wave * 512]);
    int t2b = t2a + 64;
    const u16* Ab2 = (t2b >= 0 && t2b < 256)
        ? xb + ((long)(b * 256 + t2b)) * 1024 + i0 + lc
        : zp + lc;
    gld16(Ab2, &As[2048 + wave * 512]);
    const u16* Bb = wT + (long)(n0 + arow) * 3072 + k0 + lc;
    gld16(Bb,                   &Bs[wave * 512]);
    gld16(Bb + (long)64 * 3072, &Bs[2048 + wave * 512]);
    __syncthreads();
    s8v af[4], bfr[4];
#pragma unroll
    for (int i = 0; i < 4; i++) af[i]  = *(const s8v*)&As[(wm + i * 16 + l15) * 32 + qs];
#pragma unroll
    for (int j = 0; j < 4; j++) bfr[j] = *(const s8v*)&Bs[(wn + j * 16 + l15) * 32 + qs];
#pragma unroll
    for (int i = 0; i < 4; i++)
#pragma unroll
      for (int j = 0; j < 4; j++)
        acc[i][j] = __builtin_amdgcn_mfma_f32_16x16x32_bf16(af[i], bfr[j], acc[i][j], 0, 0, 0);
    __syncthreads();
  }
#pragma unroll
  for (int j = 0; j < 4; j++) {
    int col = n0 + wn + j * 16 + l15;
    float bv = bias[col];
#pragma unroll
    for (int i = 0; i < 4; i++)
#pragma unroll
      for (int rr = 0; rr < 4; rr++) {
        int row = m0 + wm + i * 16 + quad * 4 + rr;
        float v = acc[i][j][rr] + bv;
        out[(long)row * 512 + col] = v > 0.f ? v : 0.f;
      }
  }
}

// ================= transposes / converts =================
__global__ __launch_bounds__(256) void wtrans_k(const float* __restrict__ src,
    u16* __restrict__ dst, int R, int C) {
  __shared__ float t[32][33];
  int c0 = blockIdx.x * 32, r0 = blockIdx.y * 32;
  int tx = threadIdx.x & 31, ty = threadIdx.x >> 5;
  for (int rr = 0; rr < 32; rr += 8)
    t[ty + rr][tx] = src[(long)(r0 + ty + rr) * C + c0 + tx];
  __syncthreads();
  for (int rr = 0; rr < 32; rr += 8)
    dst[(long)(c0 + ty + rr) * R + r0 + tx] = to_bf16(t[tx][ty + rr]);
}

// 8 merged 512x512 transposes (z picks src / u16-offset into ws)
struct WT8 { const float* s[8]; long doff[8]; };
__global__ __launch_bounds__(256) void wt8_k(WT8 w, u16* __restrict__ base) {
  __shared__ float t[32][33];
  int z = blockIdx.z;
  const float* src = w.s[z];
  u16* dst = base + w.doff[z];
  int c0 = blockIdx.x * 32, r0 = blockIdx.y * 32;
  int tx = threadIdx.x & 31, ty = threadIdx.x >> 5;
  for (int rr = 0; rr < 32; rr += 8)
    t[ty + rr][tx] = src[(long)(r0 + ty + rr) * 512 + c0 + tx];
  __syncthreads();
  for (int rr = 0; rr < 32; rr += 8)
    dst[(long)(c0 + ty + rr) * 512 + r0 + tx] = to_bf16(t[tx][ty + rr]);
}

__global__ __launch_bounds__(256) void convw_t(const float* __restrict__ src, u16* __restrict__ dst) {
  int id = blockIdx.x * 256 + threadIdx.x;
  if (id >= 512 * 3072) return;
  int o = id / 3072, r2 = id % 3072;
  int kp = r2 >> 10, i = r2 & 1023;
  dst[id] = to_bf16(src[(long)o * 3072 + i * 3 + kp]);
}

// y=0: a_mem->amt ; y=1: n_mem->nmt  (512x64, K padded)
__global__ __launch_bounds__(256) void memtrans2_k(const float* __restrict__ a,
    const float* __restrict__ n, u16* __restrict__ amt, u16* __restrict__ nmt) {
  int id = blockIdx.x * 256 + threadIdx.x;
  if (id >= 512 * 64) return;
  const float* src = blockIdx.y ? n : a;
  u16* dst = blockIdx.y ? nmt : amt;
  int nn = id >> 6, k = id & 63;
  dst[id] = (k < 60) ? to_bf16(src[(long)k * 512 + nn]) : (u16)0;
}

// [2][128][512] bf16, rows 60..127 zero  (MEMORY PHASE only — overlaps scores)
__global__ __launch_bounds__(256) void membpad_k(const float* __restrict__ a,
    const float* __restrict__ n, u16* __restrict__ dst) {
  int id = blockIdx.x * 256 + threadIdx.x;   // < 131072
  int mat = id >> 16, r2 = id & 65535;
  int nr = r2 >> 9, k = r2 & 511;
  const float* s = mat ? n : a;
  dst[id] = (nr < 60) ? to_bf16(s[(long)nr * 512 + k]) : (u16)0;
}

__global__ __launch_bounds__(256) void vtrans_k(const u16* __restrict__ qkv, u16* __restrict__ vt) {
  __shared__ u16 t[32][33];
  int z = blockIdx.z;
  int b = z >> 2, h2 = z & 3;
  int t0 = blockIdx.x * 32, d0 = blockIdx.y * 32;
  int tx = threadIdx.x & 31, ty = threadIdx.x >> 5;
  const u16* src = qkv + (long)b * 393216 + 1024 + h2 * 128;
  for (int rr = 0; rr < 32; rr += 8)
    t[ty + rr][tx] = src[(long)(t0 + ty + rr) * 1536 + d0 + tx];
  __syncthreads();
  u16* dst = vt + (long)z * 32768;
  for (int rr = 0; rr < 32; rr += 8)
    dst[(long)(d0 + ty + rr) * 256 + t0 + tx] = t[tx][ty + rr];
}

// vectorized fp32 -> bf16 convert, 8 elems/thread (n % 8 == 0)
__global__ __launch_bounds__(256) void cvt_k(const float* __restrict__ src, u16* __restrict__ dst, long n) {
  long i = ((long)blockIdx.x * 256 + threadIdx.x) * 8;
  if (i >= n) return;
  float4 f0 = ((const float4*)(src + i))[0];
  float4 f1 = ((const float4*)(src + i))[1];
  *(u16x8*)(dst + i) = pack8(f0, f1);
}

__global__ void zpage_k(u16* __restrict__ z) { z[threadIdx.x] = 0; }

// ================= layernorm: wave-per-row, fp32 in -> bf16 out =================
__global__ __launch_bounds__(256) void ln_k(const float* __restrict__ in,
    const float* __restrict__ g, const float* __restrict__ b, u16* __restrict__ out) {
  int wave = threadIdx.x >> 6, lane = threadIdx.x & 63;
  long row = (long)blockIdx.x * 4 + wave;
  const float* r = in + row * 512 + lane * 8;
  float4 x0 = ((const float4*)r)[0];
  float4 x1 = ((const float4*)r)[1];
  float s = x0.x + x0.y + x0.z + x0.w + x1.x + x1.y + x1.z + x1.w;
  for (int off = 32; off; off >>= 1) s += __shfl_xor(s, off);
  float mean = s * (1.f / 512.f);
  float d[8] = {x0.x - mean, x0.y - mean, x0.z - mean, x0.w - mean,
                x1.x - mean, x1.y - mean, x1.z - mean, x1.w - mean};
  float q = 0.f;
#pragma unroll
  for (int i = 0; i < 8; i++) q += d[i] * d[i];
  for (int off = 32; off; off >>= 1) q += __shfl_xor(q, off);
  float inv = rsqrtf(q * (1.f / 512.f) + 1e-5f);
  const float4* gp = (const float4*)(g + lane * 8);
  const float4* bp = (const float4*)(b + lane * 8);
  float4 g0 = gp[0], g1 = gp[1], b0 = bp[0], b1 = bp[1];
  float gv[8] = {g0.x, g0.y, g0.z, g0.w, g1.x, g1.y, g1.z, g1.w};
  float bv[8] = {b0.x, b0.y, b0.z, b0.w, b1.x, b1.y, b1.z, b1.w};
  u16x8 o;
#pragma unroll
  for (int i = 0; i < 8; i++) o[i] = to_bf16(d[i] * inv * gv[i] + bv[i]);
  *(u16x8*)(out + row * 512 + lane * 8) = o;
}

// ========== softmax: wave-per-row (rows of 256), fp32 in -> bf16 out ==========
__global__ __launch_bounds__(256) void softmax_k(const float* __restrict__ s, u16* __restrict__ d) {
  int wave = threadIdx.x >> 6, lane = threadIdx.x & 63;
  long row = (long)blockIdx.x * 4 + wave;
  const float* r = s + row * 256 + lane * 4;
  float4 v = *(const float4*)r;
  float mx = fmaxf(fmaxf(v.x, v.y), fmaxf(v.z, v.w));
  for (int off = 32; off; off >>= 1) mx = fmaxf(mx, __shfl_xor(mx, off));
  v.x = expf(v.x - mx); v.y = expf(v.y - mx); v.z = expf(v.z - mx); v.w = expf(v.w - mx);
  float sum = v.x + v.y + v.z + v.w;
  for (int off = 32; off; off >>= 1) sum += __shfl_xor(sum, off);
  float is = 1.f / sum;
  u16x4 o;
  o[0] = to_bf16(v.x * is); o[1] = to_bf16(v.y * is);
  o[2] = to_bf16(v.z * is); o[3] = to_bf16(v.w * is);
  *(u16x4*)(d + row * 256 + lane * 4) = o;
}

// y picks source block (stride 491520) -> out block {0,24576,16384,8192}
__global__ __launch_bounds__(256) void top4_k(const float* __restrict__ att, float* __restrict__ out) {
  int y = blockIdx.y;
  int i = blockIdx.x * 256 + threadIdx.x;
  if (i >= HBT) return;
  const float* a = att + (long)y * 491520 + (long)i * 60;
  float t0 = -1e30f, t1 = -1e30f, t2 = -1e30f, t3 = -1e30f;
  for (int k = 0; k < 60; k++) {
    float v = a[k];
    if (v > t0)      { t3 = t2; t2 = t1; t1 = t0; t0 = v; }
    else if (v > t1) { t3 = t2; t2 = t1; t1 = v; }
    else if (v > t2) { t3 = t2; t2 = v; }
    else if (v > t3) { t3 = v; }
  }
  int ooff = (y == 0) ? 0 : (4 - y) * 8192;
  out[ooff + i] = (t0 + t1 + t2 + t3) * 0.25f;
}

// ========== top-17 over 256: block-parallel iterative argmax; y selects source row-block
__global__ __launch_bounds__(256) void topk17_k(const float* __restrict__ tatt, int* __restrict__ idx) {
  int b = blockIdx.x, y = blockIdx.y, tid = threadIdx.x;
  __shared__ float sv[256];
  __shared__ int si[256];
  float v = tatt[(long)y * 8192 + (long)b * 256 + tid];
  int* ob = idx + y * 544 + b * 17;
  for (int s = 0; s < 17; s++) {
    sv[tid] = v; si[tid] = tid;
    __syncthreads();
    for (int off = 128; off > 0; off >>= 1) {
      if (tid < off) {
        float v2 = sv[tid + off]; int i2 = si[tid + off];
        if (v2 > sv[tid] || (v2 == sv[tid] && i2 < si[tid])) { sv[tid] = v2; si[tid] = i2; }
      }
      __syncthreads();
    }
    int win = si[0];
    if (tid == 0) ob[s] = win;
    if (tid == win) v = -1e30f;
    __syncthreads();
  }
}

__device__ inline void gmean_body(const float* feats, const int* idx, float* out, int b, int tid) {
  float s0 = 0.f, s1 = 0.f;
  for (int j = 0; j < 17; j++) {
    int t = idx[b * 17 + j];
    const float* r = feats + ((long)b * 256 + t) * 512;
    s0 += r[tid]; s1 += r[tid + 256];
  }
  out[(long)b * 512 + tid]       = s0 * (1.f / 17.f);
  out[(long)b * 512 + tid + 256] = s1 * (1.f / 17.f);
}

// y=0: (Ax, idxA)->NEG ; y=1: (Nx, idxN)->ANC ; y=2: (Ax, idxP)->POS
__global__ __launch_bounds__(256) void gmean3_k(const float* __restrict__ Ax,
    const float* __restrict__ Nx, const int* __restrict__ idx0, float* __restrict__ ob) {
  int b = blockIdx.x, y = blockIdx.y, tid = threadIdx.x;
  const float* feats = (y == 1) ? Nx : Ax;
  const int* idx = idx0 + y * 544;
  float* out = ob + (long)((y + 2) % 3) * 16384;
  gmean_body(feats, idx, out, b, tid);
}

// y=0: (f0=nnew, idxN)->ANEW ; y=1: (f1=R0, idxA)->NNEG
__global__ __launch_bounds__(256) void gmean2_k(const float* __restrict__ f0,
    const float* __restrict__ f1, const int* __restrict__ idx0, float* __restrict__ ob) {
  int b = blockIdx.x, y = blockIdx.y, tid = threadIdx.x;
  const float* feats = y ? f1 : f0;
  const int* idx = idx0 + (y == 0 ? 544 : 0);
  float* out = ob + (long)y * 16384;
  gmean_body(feats, idx, out, b, tid);
}

// vae: nnew may alias mu (elementwise read-before-write)
__global__ __launch_bounds__(256) void vae_k(const float* __restrict__ mu,
    const float* __restrict__ var, const float* __restrict__ eps,
    float* __restrict__ nnew, float* __restrict__ accum) {
  constexpr long N4 = HHf / 4;
  long stride = (long)gridDim.x * 256;
  float kle = 0.f;
  for (long i = (long)blockIdx.x * 256 + threadIdx.x; i < N4; i += stride) {
    float4 m4 = ((const float4*)mu)[i];
    float4 v4 = ((const float4*)var)[i];
    float4 e4 = ((const float4*)eps)[i];
    float4 o;
    float ev;
    ev = expf(v4.x); o.x = m4.x + e4.x * sqrtf(ev); kle += 1.f + v4.x - m4.x * m4.x - ev;
    ev = expf(v4.y); o.y = m4.y + e4.y * sqrtf(ev); kle += 1.f + v4.y - m4.y * m4.y - ev;
    ev = expf(v4.z); o.z = m4.z + e4.z * sqrtf(ev); kle += 1.f + v4.z - m4.z * m4.z - ev;
    ev = expf(v4.w); o.w = m4.w + e4.w * sqrtf(ev); kle += 1.f + v4.w - m4.w * m4.w - ev;
    ((float4*)nnew)[i] = o;
  }
  __shared__ float sm[256];
  float s = bred_sum(kle, sm, threadIdx.x);
  if (threadIdx.x == 0) atomicAdd(accum + 0, s);
}

__global__ __launch_bounds__(256) void tripcos_k(const float* __restrict__ anc,
    const float* __restrict__ pos, const float* __restrict__ neg, float* __restrict__ accum) {
  int b = blockIdx.x, tid = threadIdx.x;
  const float *a = anc + (long)b * 512, *p = pos + (long)b * 512, *n = neg + (long)b * 512;
  float a0 = a[tid], a1 = a[tid + 256], p0 = p[tid], p1 = p[tid + 256], n0 = n[tid], n1 = n[tid + 256];
  __shared__ float sm[256];
  float sa  = bred_sum(a0 * a0 + a1 * a1, sm, tid);
  float sp  = bred_sum(p0 * p0 + p1 * p1, sm, tid);
  float sn  = bred_sum(n0 * n0 + n1 * n1, sm, tid);
  float dot = bred_sum(a0 * n0 + a1 * n1, sm, tid);
  float na = sqrtf(sa), np_ = sqrtf(sp), nn = sqrtf(sn);
  float ina = 1.f / na, inp = 1.f / np_, inn = 1.f / nn;
  float d0 = a0 * ina - p0 * inp + 1e-6f, d1 = a1 * ina - p1 * inp + 1e-6f;
  float e0 = a0 * ina - n0 * inn + 1e-6f, e1 = a1 * ina - n1 * inn + 1e-6f;
  float dp2 = bred_sum(d0 * d0 + d1 * d1, sm, tid);
  float dn2 = bred_sum(e0 * e0 + e1 * e1, sm, tid);
  if (tid == 0) {
    float dp = sqrtf(dp2), dn = sqrtf(dn2);
    float t = dp - dn + 1.f;
    atomicAdd(accum + 1, t > 0.f ? t : 0.f);
    float c = 1.f - dot / (fmaxf(na, 1e-6f) * fmaxf(nn, 1e-6f));
    atomicAdd(accum + 2, c);
  }
}

__global__ __launch_bounds__(256) void dist_k(const float* __restrict__ anew,
    const float* __restrict__ nneg, float* __restrict__ accum) {
  int b = blockIdx.x, tid = threadIdx.x;
  const float *a = anew + (long)b * 512, *n = nneg + (long)b * 512;
  float a0 = a[tid], a1 = a[tid + 256], n0 = n[tid], n1 = n[tid + 256];
  __shared__ float sm[256];
  float sa = bred_sum(a0 * a0 + a1 * a1, sm, tid);
  float sn = bred_sum(n0 * n0 + n1 * n1, sm, tid);
  if (tid == 0) {
    float v = 100.f - sqrtf(sn) + sqrtf(sa);
    atomicAdd(accum + 3, v > 0.f ? v : 0.f);
  }
}

// float4 version: 4 elems/thread; grid 8192
__global__ __launch_bounds__(256) void xout_k(const float* __restrict__ emb,
    const float* __restrict__ nnew, const float* __restrict__ anm,
    const float* __restrict__ anew, const float* __restrict__ nam,
    float* __restrict__ xout) {
  long q = (long)blockIdx.x * 256 + threadIdx.x;   // float4 index, < 2097152
  long i = q * 4;
  long row = i >> 9;
  int d = (int)(i & 511);
  long o = row * 1024 + d;
  *(float4*)(xout + o) = ((const float4*)emb)[q];
  float4 v;
  if (i < HHf) {
    float4 a = ((const float4*)nnew)[q];
    float4 b = ((const float4*)anm)[q];
    v.x = a.x + b.x; v.y = a.y + b.y; v.z = a.z + b.z; v.w = a.w + b.w;
  } else {
    long q2 = q - HHf / 4;
    float4 a = ((const float4*)anew)[q2];
    float4 b = ((const float4*)nam)[q2];
    v.x = a.x + b.x; v.y = a.y + b.y; v.z = a.z + b.z; v.w = a.w + b.w;
  }
  *(float4*)(xout + o + 512) = v;
}

__global__ __launch_bounds__(256) void vfeat_k(const float* __restrict__ emb, float* __restrict__ vf) {
  __shared__ float tile[32][33];
  int b = blockIdx.z;
  int t0 = blockIdx.x * 32, d0 = blockIdx.y * 32;
  int tx = threadIdx.x & 31, ty = threadIdx.x >> 5;
  for (int r = 0; r < 32; r += 8)
    tile[ty + r][tx] = emb[((long)b * 256 + t0 + ty + r) * 512 + d0 + tx];
  __syncthreads();
  for (int r = 0; r < 32; r += 8)
    vf[((long)b * 512 + d0 + ty + r) * 256 + t0 + tx] = tile[tx][ty + r];
}

__global__ void init_k(float* accum) {
  accum[0] = 0.f; accum[1] = 0.f; accum[2] = 0.f; accum[3] = 0.f;
}

__global__ void fin_k(const float* __restrict__ accum, float* __restrict__ out) {
  out[0] = accum[1] * (1.f / 32.f);
  out[1] = -0.5f * accum[0] * (1.f / 16384.f);
  out[2] = accum[3] * (1.f / 32.f);
  out[OO_COS] = accum[2] * (1.f / 32.f);
}

static inline GP2 mk(const void* A, const void* B, const float* bias, void* C,
                     int M, int N, int K, int lda, int ldb, int ldc,
                     float scale = 1.f, int Hdiv = 1,
                     long sAb = 0, long sAh = 0, long sBb = 0, long sBh = 0,
                     long sCb = 0, long sCh = 0, const float* bias2 = nullptr,
                     u16* C2 = nullptr) {
  GP2 p; p.A = A; p.B = B; p.bias = bias; p.C = C; p.bias2 = bias2; p.C2 = C2;
  p.M = M; p.N = N; p.K = K; p.lda = lda; p.ldb = ldb; p.ldc = ldc;
  p.Hdiv = Hdiv; p.sAb = sAb; p.sAh = sAh; p.sBb = sBb; p.sBh = sBh;
  p.sCb = sCb; p.sCh = sCh; p.scale = scale;
  return p;
}

} // namespace

extern "C" void kernel_launch(void* const* d_in, const int* in_sizes, int n_in,
                              void* d_out, int out_size, void* d_ws, size_t ws_size,
                              hipStream_t stream) {
  const float* x      = (const float*)d_in[0];
  const float* epsi   = (const float*)d_in[1];
  const float* conv_w = (const float*)d_in[2];
  const float* conv_b = (const float*)d_in[3];
  const float* ln1_g  = (const float*)d_in[4];
  const float* ln1_b  = (const float*)d_in[5];
  const float* qkv_w  = (const float*)d_in[6];
  const float* out_w  = (const float*)d_in[7];
  const float* out_b  = (const float*)d_in[8];
  const float* ln2_g  = (const float*)d_in[9];
  const float* ln2_b  = (const float*)d_in[10];
  const float* ff1_w  = (const float*)d_in[11];
  const float* ff1_b  = (const float*)d_in[12];
  const float* ff2_w  = (const float*)d_in[13];
  const float* ff2_b  = (const float*)d_in[14];
  const float* a_mem  = (const float*)d_in[15];
  const float* n_mem  = (const float*)d_in[16];
  const float* mu_w   = (const float*)d_in[17];
  const float* mu_b   = (const float*)d_in[18];
  const float* var_w  = (const float*)d_in[19];
  const float* var_b  = (const float*)d_in[20];
  float* out = (float*)d_out;
  float* ws  = (float*)d_ws;

  const float ATTSCALE = 0.08838834764831845f;
  const float SIGSCALE = 0.04419417382415922f;

  float* h   = ws + F_H;
  u16* lnb   = (u16*)(ws + F_LNB);
  u16* qkvb  = (u16*)(ws + F_QKV);
  u16* vtb   = (u16*)(ws + F_VT);
  float* scf = ws + F_SC;
  u16* scb   = qkvb;                  // bf16 P (softmax out) reuses qkv region
  u16* wqkvT = (u16*)(ws + W_QKV);
  u16* woutT = (u16*)(ws + W_OUT);
  u16* wff1T = (u16*)(ws + W_FF1);
  u16* wff2T = (u16*)(ws + W_FF2);
  u16* wmuT  = (u16*)(ws + W_MU);
  u16* wconvT= (u16*)(ws + W_CONV);
  u16* amtT  = (u16*)(ws + W_AMT);
  u16* nmtT  = (u16*)(ws + W_NMT);
  u16* membT = (u16*)(ws + W_MEMB);   // [2][128][512] bf16 zero-padded (memory phase)
  u16* zpage = (u16*)(ws + Z_PG);
  u16* xb    = (u16*)(ws + F_QKV);    // x in bf16 (conv phase only)

  // ---- weight transposes ----
  wtrans_k<<<dim3(48, 16), 256, 0, stream>>>(qkv_w,          wqkvT,          512, 1536);
  wtrans_k<<<dim3(48, 16), 256, 0, stream>>>(qkv_w + 786432, wqkvT + 786432, 512, 1536);
  {
    WT8 w;
    w.s[0] = out_w;          w.doff[0] = 2 * W_OUT;
    w.s[1] = out_w + 262144; w.doff[1] = 2 * W_OUT + 262144;
    w.s[2] = ff1_w;          w.doff[2] = 2 * W_FF1;
    w.s[3] = ff1_w + 262144; w.doff[3] = 2 * W_FF1 + 262144;
    w.s[4] = ff2_w;          w.doff[4] = 2 * W_FF2;
    w.s[5] = ff2_w + 262144; w.doff[5] = 2 * W_FF2 + 262144;
    w.s[6] = mu_w;           w.doff[6] = 2 * W_MU;
    w.s[7] = var_w;          w.doff[7] = 2 * W_VAR;
    wt8_k<<<dim3(16, 16, 8), 256, 0, stream>>>(w, (u16*)ws);
  }
  convw_t<<<6144, 256, 0, stream>>>(conv_w, wconvT);
  memtrans2_k<<<dim3(128, 2), 256, 0, stream>>>(a_mem, n_mem, amtT, nmtT);

  // ---- conv + relu -> h (A via bf16 x + global_load_lds) ----
  cvt_k<<<8192, 256, 0, stream>>>(x, xb, 16777216);
  zpage_k<<<1, 256, 0, stream>>>(zpage);
  convm_k<<<dim3(128, 4), 256, 0, stream>>>(xb, zpage, wconvT, conv_b, h);

  // ---- transformer ----
  u16* hb = lnb;
  for (int i = 0; i < 2; i++) {
    ln_k<<<4096, 256, 0, stream>>>(h, ln1_g + i * 512, ln1_b + i * 512, lnb);
    {
      GP2 p = mk(lnb, wqkvT + (long)i * 786432, nullptr, qkvb, 16384, 1536, 512, 512, 512, 1536);
      mgemm_k<0, true, true, false, true, true><<<dim3(128, 12, 1), 256, 0, stream>>>(p);
    }
    vtrans_k<<<dim3(8, 4, 256), 256, 0, stream>>>(qkvb, vtb);
    {
      GP2 p = mk(qkvb, qkvb + 512, nullptr, scf, 256, 256, 128, 1536, 1536, 256,
                 ATTSCALE, 4, 393216, 128, 393216, 128, 262144, 65536);
      mgemm_k<0, true, true, false, false, true><<<dim3(2, 2, 256), 256, 0, stream>>>(p);
    }
    // softmax: fp32 scores -> bf16 P (overwrites dead Q/K rows; V already in vtb)
    softmax_k<<<16384, 256, 0, stream>>>(scf, scb);
    {
      GP2 p = mk(scb, vtb, nullptr, lnb, 256, 128, 256, 256, 256, 512,
                 1.f, 4, 262144, 65536, 131072, 32768, 131072, 128);
      mgemm_k<0, true, true, false, true, true><<<dim3(2, 1, 256), 256, 0, stream>>>(p);
    }
    {
      GP2 p = mk(lnb, woutT + (long)i * 262144, out_b + i * 512, h, 16384, 512, 512, 512, 512, 512);
      mgemm_k<0, true, true, true, false, true><<<dim3(128, 4, 1), 256, 0, stream>>>(p);
    }
    ln_k<<<4096, 256, 0, stream>>>(h, ln2_g + i * 512, ln2_b + i * 512, lnb);
    {
      GP2 p = mk(lnb, wff1T + (long)i * 262144, ff1_b + i * 512, qkvb, 16384, 512, 512, 512, 512, 512);
      mgemm_k<1, true, true, false, true, true><<<dim3(128, 4, 1), 256, 0, stream>>>(p);
    }
    if (i == 0) {
      GP2 p = mk(qkvb, wff2T, ff2_b, h, 16384, 512, 512, 512, 512, 512);
      mgemm_k<0, true, true, true, false, true><<<dim3(128, 4, 1), 256, 0, stream>>>(p);
    } else {
      // layer 1 ff2: fused dual write — fp32 h (residual acc) + bf16 hb
      GP2 p = mk(qkvb, wff2T + 262144, ff2_b + 512, h, 16384, 512, 512, 512, 512, 512,
                 1.f, 1, 0, 0, 0, 0, 0, 0, nullptr, hb);
      mgemm_k<0, true, true, true, false, true, true><<<dim3(128, 4, 1), 256, 0, stream>>>(p);
    }
  }

  // ---- memory phase (hb already written by fused ff2 epilogue) ----
  membpad_k<<<512, 256, 0, stream>>>(a_mem, n_mem, membT);
  const float* Nx = h;
  const float* Ax = h + HHf;
  const u16* Axb = hb + HHf;
  float* attA  = ws + F_ATT;
  float* attN  = ws + F_ATT + 1474560;

  // 4 att GEMMs, one GL launch: bb picks Ax/Nx, hh picks a_mem/n_mem (padded B)
  {
    GP2 p = mk(Axb, membT, nullptr, attA, HBT, 60, 512, 512, 512, 60, SIGSCALE,
               2, -(long)HHf, 0, 0, 65536, 983040, 491520);
    mgemm_k<2, true, true, false, false, true><<<dim3(64, 1, 4), 256, 0, stream>>>(p);
  }

  // merged 4-way top4
  top4_k<<<dim3(32, 4), 256, 0, stream>>>(attA, out + OO_AATT);

  // 4 aug GEMMs in one launch; C order: augA, augNA, augAN, augN
  u16* augb = (u16*)(ws + F_AUG);
  u16* augA  = augb;
  u16* augN  = augb + 3 * HHf;
  {
    GP2 p = mk(attA, amtT, nullptr, augA, HBT, 512, 60, 60, 64, 512, 1.f,
               2, 983040, 491520, 0, 32768, 2 * HHf, HHf);
    mgemm_k<0, false, true, false, true, false><<<dim3(64, 4, 4), 256, 0, stream>>>(p);
  }

  float* accum = ws + O_ACC;
  int* idxA = (int*)(ws + O_IDX);
  init_k<<<1, 1, 0, stream>>>(accum);

  topk17_k<<<dim3(32, 3), 256, 0, stream>>>(out + OO_AATT, idxA);
  gmean3_k<<<dim3(32, 3), 256, 0, stream>>>(Ax, Nx, idxA, ws + O_ANC);
  tripcos_k<<<32, 256, 0, stream>>>(ws + O_ANC, ws + O_POS, ws + O_NEG, accum);

  // round1: augN @ {mu,var} in one launch
  {
    GP2 p = mk(augN, wmuT, mu_b, ws + F_MU, HBT, 512, 512, 512, 512, 512, 1.f,
               2, 0, 0, 0, 262144, 0, 4194304, var_b);
    mgemm_k<0, true, true, false, false, true><<<dim3(64, 4, 2), 256, 0, stream>>>(p);
  }
  vae_k<<<512, 256, 0, stream>>>(ws + F_MU, ws + F_VAR, epsi, ws + F_MU, accum);

  // round2: {augA, augNA, augAN} @ mu -> {R0=anew, R1=nam, R2=anm}
  {
    GP2 p = mk(augA, wmuT, mu_b, ws + F_R0, HBT, 512, 512, 512, 512, 512, 1.f,
               1, HHf, 0, 0, 0, 4194304, 0);
    mgemm_k<0, true, true, false, false, true><<<dim3(64, 4, 3), 256, 0, stream>>>(p);
  }

  gmean2_k<<<dim3(32, 2), 256, 0, stream>>>(ws + F_MU, ws + F_R0, idxA, ws + O_ANEW);
  dist_k<<<32, 256, 0, stream>>>(ws + O_ANEW, ws + O_NNEG, accum);

  xout_k<<<8192, 256, 0, stream>>>(h, ws + F_MU, ws + F_R2, ws + F_R0, ws + F_R1,
                                   out + OO_XOUT);
  vfeat_k<<<dim3(8, 16, 64), 256, 0, stream>>>(h, out + OO_VFEAT);
  fin_k<<<1, 1, 0, stream>>>(accum, out);
}

// Round 15
// 903.584 us; speedup vs baseline: 1.2226x; 1.0586x over previous
//
#include <hip/hip_runtime.h>
#include <math.h>

namespace {

typedef unsigned short u16;
typedef __attribute__((ext_vector_type(8))) short s8v;
typedef __attribute__((ext_vector_type(8))) unsigned short u16x8;
typedef __attribute__((ext_vector_type(4))) unsigned short u16x4;
typedef __attribute__((ext_vector_type(4))) float f32x4;
typedef __attribute__((ext_vector_type(4))) unsigned int u32x4;

constexpr int HBT = 8192;            // 32*256
constexpr long HHf = 4194304;        // 8192*512

// ---- workspace offsets (float units) ----
constexpr long F_H    = 0;           // h / x_emb fp32 (8388608)
constexpr long F_LNB  = 8388608;     // ln / o / hbf bf16
constexpr long F_QKV  = 12582912;    // qkv bf16; xb during conv; P (bf16) after softmax; ff1 out
constexpr long F_VT   = 25165824;    // v^T bf16
constexpr long F_SC   = 29360128;    // scores fp32 (16777216) -> region ends 46137344
// phase M (QKV/VT/SC regions dead):
constexpr long F_ATT  = 12582912;    // 4 x 491520 fp32: attA, attNA, attAN, attN
constexpr long F_AUG  = 14548992;    // 4 x 4194304 u16: augA, augNA, augAN, augN
constexpr long F_MU   = 22937600;    // fp32 (round1 mu out; vae overwrites with nnew)
constexpr long F_VAR  = 27131904;    // round1 var out
constexpr long F_R0   = 31326208;    // round2: A_aug_new
constexpr long F_R1   = 35520512;    // round2: N_Aaug_m (nam)
constexpr long F_R2   = 39714816;    // round2: A_Naug_m (anm)
// membT overlaps the (dead-by-then) scores region; filled in MEMORY PHASE only.
constexpr long W_MEMB = 43909120;    // bf16 [2][128][512] zero-padded (131072 u16 = 65536 fl)
constexpr long Z_PG   = 43974656;    // zero page (256 u16) — conv phase only
// transposed weights (bf16), live whole launch:
constexpr long W_QKV  = 46137344;    // 2 x 786432 u16
constexpr long W_OUT  = 46923776;    // 2 x 262144 u16
constexpr long W_FF1  = 47185920;
constexpr long W_FF2  = 47448064;
constexpr long W_MU   = 47710208;    // 262144 u16
constexpr long W_VAR  = 47841280;
constexpr long W_CONV = 47972352;    // 1572864 u16
constexpr long W_AMT  = 48758784;    // 32768 u16 (512x64 padded)
constexpr long W_NMT  = 48775168;
constexpr long O_ANC  = 48791552;
constexpr long O_POS  = O_ANC + 16384;
constexpr long O_NEG  = O_POS + 16384;
constexpr long O_ANEW = O_NEG + 16384;
constexpr long O_NNEG = O_ANEW + 16384;
constexpr long O_IDX  = O_NNEG + 16384;   // 3*544 ints
constexpr long O_ACC  = O_IDX + 1632;     // 4 floats

// ---- output offsets ----
constexpr long OO_AATT  = 3;
constexpr long OO_NATT  = 3 + 8192;
constexpr long OO_ANATT = 3 + 16384;
constexpr long OO_NAATT = 3 + 24576;
constexpr long OO_COS   = 32771;
constexpr long OO_XOUT  = 32772;
constexpr long OO_VFEAT = 32772L + 16777216L;

__device__ inline u16 to_bf16(float f) {
  union { float f; unsigned u; } x; x.f = f;
  unsigned r = x.u + 0x7fffu + ((x.u >> 16) & 1u);
  return (u16)(r >> 16);
}
__device__ inline u16x8 pack8(float4 a, float4 b) {
  u16x8 r;
  r[0]=to_bf16(a.x); r[1]=to_bf16(a.y); r[2]=to_bf16(a.z); r[3]=to_bf16(a.w);
  r[4]=to_bf16(b.x); r[5]=to_bf16(b.y); r[6]=to_bf16(b.z); r[7]=to_bf16(b.w);
  return r;
}

// async global->LDS, 16B per lane; LDS dest = wave-uniform base + lane*16
typedef __attribute__((address_space(1))) void gvoid;
typedef __attribute__((address_space(3))) void lvoid;
__device__ inline void gld16(const u16* g, u16* l) {
  __builtin_amdgcn_global_load_lds((gvoid*)g, (lvoid*)l, 16, 0, 0);
}

__device__ inline float bred_sum(float v, float* sm, int tid) {
  sm[tid] = v; __syncthreads();
  for (int s = 128; s > 0; s >>= 1) { if (tid < s) sm[tid] += sm[tid + s]; __syncthreads(); }
  float r = sm[0]; __syncthreads();
  return r;
}

struct GP2 {
  const void* A; const void* B; const float* bias; void* C;
  const float* bias2;   // used for hh==1 when non-null
  u16* C2;              // optional secondary bf16 output (D2)
  int M, N, K, lda, ldb, ldc, Hdiv;
  long sAb, sAh, sBb, sBh, sCb, sCh;
  float scale;
};

// GL path (BK=64): LDS tile [128 rows][8 pieces of 16B]; physical piece =
// logical ^ (row&7). Write: linear dest + pre-swizzled global col. Read:
// piece (kh*4+quad) ^ (l15&7). 2 lanes/piece residual = free (m136).
// Non-GL path (BK=32): [128 rows][4 pieces]; piece = logical ^ ((row>>1)&3).

// ================= bf16 MFMA GEMM: C = epi(scale*A@B^T + bias) =================
// GL requires ABF&&BBF, M,N%128==0, K%64==0. D2: extra bf16 store to C2.
template<int EPI, bool ABF, bool BBF, bool ACC, bool CBF, bool GL, bool D2 = false>
__global__ __launch_bounds__(256) void mgemm_k(GP2 p) {
  __shared__ __align__(16) u16 As[8192];
  __shared__ __align__(16) u16 Bs[8192];
  int bb = blockIdx.z / p.Hdiv, hh = blockIdx.z % p.Hdiv;
  long aoff = (long)bb * p.sAb + (long)hh * p.sAh;
  long boff = (long)bb * p.sBb + (long)hh * p.sBh;
  long coff = (long)bb * p.sCb + (long)hh * p.sCh;
  int m0 = blockIdx.x * 128, n0 = blockIdx.y * 128;
  int tid = threadIdx.x, r = tid & 127, seg = tid >> 7;
  int lane = tid & 63, wave = tid >> 6;
  int wm = (wave >> 1) * 64, wn = (wave & 1) * 64;
  int l15 = lane & 15, quad = lane >> 4;
  f32x4 acc[4][4] = {};
  if constexpr (GL) {
    int lr8 = lane >> 3;                         // 0..7 row within wave-slab
    int lc = ((lane & 7) ^ lr8) * 8;             // pre-swizzled global col (u16)
    const u16* Abase = (const u16*)p.A + aoff + lc;
    const u16* Bbase = (const u16*)p.B + boff + lc;
    for (int k0 = 0; k0 < p.K; k0 += 64) {
#pragma unroll
      for (int rr = 0; rr < 4; rr++) {
        int row = rr * 32 + wave * 8 + lr8;
        gld16(Abase + (long)(m0 + row) * p.lda + k0, &As[rr * 2048 + wave * 512]);
        gld16(Bbase + (long)(n0 + row) * p.ldb + k0, &Bs[rr * 2048 + wave * 512]);
      }
      __syncthreads();
#pragma unroll
      for (int kh = 0; kh < 2; kh++) {
        int qs = (((kh << 2) + quad) ^ (l15 & 7)) * 8;
        s8v af[4], bfr[4];
#pragma unroll
        for (int i = 0; i < 4; i++) af[i]  = *(const s8v*)&As[(wm + i * 16 + l15) * 64 + qs];
#pragma unroll
        for (int j = 0; j < 4; j++) bfr[j] = *(const s8v*)&Bs[(wn + j * 16 + l15) * 64 + qs];
#pragma unroll
        for (int i = 0; i < 4; i++)
#pragma unroll
          for (int j = 0; j < 4; j++)
            acc[i][j] = __builtin_amdgcn_mfma_f32_16x16x32_bf16(af[i], bfr[j], acc[i][j], 0, 0, 0);
      }
      __syncthreads();
    }
  } else {
    int rs = (r >> 1) & 3;
    int qs = (quad ^ ((l15 >> 1) & 3)) * 8;
    for (int k0 = 0; k0 < p.K; k0 += 32) {
      bool kfull = (k0 + 32 <= p.K);
      int p0 = ((2 * seg) ^ rs) * 8;
      int p1 = ((2 * seg + 1) ^ rs) * 8;
      { // A stage
        int gm = m0 + r;
        if (ABF) {
          const u16* Ar = (const u16*)p.A + aoff + (long)gm * p.lda + k0 + seg * 16;
          if (kfull) {
            *(u32x4*)&As[r * 32 + p0] = *(const u32x4*)Ar;
            *(u32x4*)&As[r * 32 + p1] = *(const u32x4*)(Ar + 8);
          } else {
            for (int c = 0; c < 16; c++) {
              int kk = k0 + seg * 16 + c;
              int cc = seg * 16 + c;
              As[r * 32 + (((cc >> 3) ^ rs) << 3) + (cc & 7)] = (kk < p.K) ? Ar[c] : (u16)0;
            }
          }
        } else {
          const float* Ar = (const float*)p.A + aoff + (long)gm * p.lda + k0 + seg * 16;
          if (kfull) {
            float4 f0 = ((const float4*)Ar)[0];
            float4 f1 = ((const float4*)Ar)[1];
            float4 f2 = ((const float4*)Ar)[2];
            float4 f3 = ((const float4*)Ar)[3];
            *(u16x8*)&As[r * 32 + p0] = pack8(f0, f1);
            *(u16x8*)&As[r * 32 + p1] = pack8(f2, f3);
          } else {
            for (int c = 0; c < 16; c++) {
              int kk = k0 + seg * 16 + c;
              int cc = seg * 16 + c;
              As[r * 32 + (((cc >> 3) ^ rs) << 3) + (cc & 7)] = (kk < p.K) ? to_bf16(Ar[c]) : (u16)0;
            }
          }
        }
      }
      { // B stage (N x K)
        int gn = n0 + r;
        bool nv = gn < p.N;
        if (BBF) {
          const u16* Br = (const u16*)p.B + boff + (long)gn * p.ldb + k0 + seg * 16;
          if (nv && kfull) {
            *(u32x4*)&Bs[r * 32 + p0] = *(const u32x4*)Br;
            *(u32x4*)&Bs[r * 32 + p1] = *(const u32x4*)(Br + 8);
          } else {
            for (int c = 0; c < 16; c++) {
              int kk = k0 + seg * 16 + c;
              int cc = seg * 16 + c;
              Bs[r * 32 + (((cc >> 3) ^ rs) << 3) + (cc & 7)] = (nv && kk < p.K) ? Br[c] : (u16)0;
            }
          }
        } else {
          const float* Br = (const float*)p.B + boff + (long)gn * p.ldb + k0 + seg * 16;
          if (nv && kfull) {
            float4 f0 = ((const float4*)Br)[0];
            float4 f1 = ((const float4*)Br)[1];
            float4 f2 = ((const float4*)Br)[2];
            float4 f3 = ((const float4*)Br)[3];
            *(u16x8*)&Bs[r * 32 + p0] = pack8(f0, f1);
            *(u16x8*)&Bs[r * 32 + p1] = pack8(f2, f3);
          } else {
            for (int c = 0; c < 16; c++) {
              int kk = k0 + seg * 16 + c;
              int cc = seg * 16 + c;
              Bs[r * 32 + (((cc >> 3) ^ rs) << 3) + (cc & 7)] = (nv && kk < p.K) ? to_bf16(Br[c]) : (u16)0;
            }
          }
        }
      }
      __syncthreads();
      s8v af[4], bfr[4];
#pragma unroll
      for (int i = 0; i < 4; i++) af[i]  = *(const s8v*)&As[(wm + i * 16 + l15) * 32 + qs];
#pragma unroll
      for (int j = 0; j < 4; j++) bfr[j] = *(const s8v*)&Bs[(wn + j * 16 + l15) * 32 + qs];
#pragma unroll
      for (int i = 0; i < 4; i++)
#pragma unroll
        for (int j = 0; j < 4; j++)
          acc[i][j] = __builtin_amdgcn_mfma_f32_16x16x32_bf16(af[i], bfr[j], acc[i][j], 0, 0, 0);
      __syncthreads();
    }
  }
  const float* bp = (p.bias2 && (hh & 1)) ? p.bias2 : p.bias;
#pragma unroll
  for (int j = 0; j < 4; j++) {
    int col = n0 + wn + j * 16 + l15;
    if (col >= p.N) continue;
    float bv = bp ? bp[col] : 0.f;
#pragma unroll
    for (int i = 0; i < 4; i++) {
#pragma unroll
      for (int rr = 0; rr < 4; rr++) {
        int row = m0 + wm + i * 16 + quad * 4 + rr;
        float v = acc[i][j][rr] * p.scale + bv;
        if (EPI == 1) v = 0.5f * v * (1.f + erff(v * 0.70710678118654752f));
        if (EPI == 2) v = 1.f / (1.f + expf(-v));
        long ci = coff + (long)row * p.ldc + col;
        if (CBF) ((u16*)p.C)[ci] = to_bf16(v);
        else {
          float* Cp = (float*)p.C;
          if (ACC) v += Cp[ci];
          Cp[ci] = v;
          if (D2) p.C2[ci] = to_bf16(v);
        }
      }
    }
  }
}

// ================= conv1d k=3 pad=1, implicit im2col MFMA (BK=64) =================
// A staged via global_load_lds from bf16 x; OOB halo rows -> zero page
__global__ __launch_bounds__(256) void convm_k(const u16* __restrict__ xb,
    const u16* __restrict__ zp, const u16* __restrict__ wT,
    const float* __restrict__ bias, float* __restrict__ out) {
  __shared__ __align__(16) u16 As[8192];
  __shared__ __align__(16) u16 Bs[8192];
  int m0 = blockIdx.x * 128, n0 = blockIdx.y * 128;
  int b = m0 >> 8, tb = m0 & 255;
  int tid = threadIdx.x;
  int lane = tid & 63, wave = tid >> 6;
  int wm = (wave >> 1) * 64, wn = (wave & 1) * 64;
  int l15 = lane & 15, quad = lane >> 4;
  int lr8 = lane >> 3;
  int lc = ((lane & 7) ^ lr8) * 8;               // pre-swizzled global col
  f32x4 acc[4][4] = {};
  for (int k0 = 0; k0 < 3072; k0 += 64) {
    int kp = k0 >> 10, i0 = (k0 & 1023);         // uniform within step (1024%64==0)
#pragma unroll
    for (int rr = 0; rr < 4; rr++) {
      int row = rr * 32 + wave * 8 + lr8;
      int t2 = tb + row + kp - 1;
      const u16* Aa = (t2 >= 0 && t2 < 256)
          ? xb + ((long)(b * 256 + t2)) * 1024 + i0 + lc
          : zp + lc;
      gld16(Aa, &As[rr * 2048 + wave * 512]);
      const u16* Bb = wT + (long)(n0 + row) * 3072 + k0 + lc;
      gld16(Bb, &Bs[rr * 2048 + wave * 512]);
    }
    __syncthreads();
#pragma unroll
    for (int kh = 0; kh < 2; kh++) {
      int qs = (((kh << 2) + quad) ^ (l15 & 7)) * 8;
      s8v af[4], bfr[4];
#pragma unroll
      for (int i = 0; i < 4; i++) af[i]  = *(const s8v*)&As[(wm + i * 16 + l15) * 64 + qs];
#pragma unroll
      for (int j = 0; j < 4; j++) bfr[j] = *(const s8v*)&Bs[(wn + j * 16 + l15) * 64 + qs];
#pragma unroll
      for (int i = 0; i < 4; i++)
#pragma unroll
        for (int j = 0; j < 4; j++)
          acc[i][j] = __builtin_amdgcn_mfma_f32_16x16x32_bf16(af[i], bfr[j], acc[i][j], 0, 0, 0);
    }
    __syncthreads();
  }
#pragma unroll
  for (int j = 0; j < 4; j++) {
    int col = n0 + wn + j * 16 + l15;
    float bv = bias[col];
#pragma unroll
    for (int i = 0; i < 4; i++)
#pragma unroll
      for (int rr = 0; rr < 4; rr++) {
        int row = m0 + wm + i * 16 + quad * 4 + rr;
        float v = acc[i][j][rr] + bv;
        out[(long)row * 512 + col] = v > 0.f ? v : 0.f;
      }
  }
}

// ================= transposes / converts =================
__global__ __launch_bounds__(256) void wtrans_k(const float* __restrict__ src,
    u16* __restrict__ dst, int R, int C) {
  __shared__ float t[32][33];
  int c0 = blockIdx.x * 32, r0 = blockIdx.y * 32;
  int tx = threadIdx.x & 31, ty = threadIdx.x >> 5;
  for (int rr = 0; rr < 32; rr += 8)
    t[ty + rr][tx] = src[(long)(r0 + ty + rr) * C + c0 + tx];
  __syncthreads();
  for (int rr = 0; rr < 32; rr += 8)
    dst[(long)(c0 + ty + rr) * R + r0 + tx] = to_bf16(t[tx][ty + rr]);
}

// 8 merged 512x512 transposes (z picks src / u16-offset into ws)
struct WT8 { const float* s[8]; long doff[8]; };
__global__ __launch_bounds__(256) void wt8_k(WT8 w, u16* __restrict__ base) {
  __shared__ float t[32][33];
  int z = blockIdx.z;
  const float* src = w.s[z];
  u16* dst = base + w.doff[z];
  int c0 = blockIdx.x * 32, r0 = blockIdx.y * 32;
  int tx = threadIdx.x & 31, ty = threadIdx.x >> 5;
  for (int rr = 0; rr < 32; rr += 8)
    t[ty + rr][tx] = src[(long)(r0 + ty + rr) * 512 + c0 + tx];
  __syncthreads();
  for (int rr = 0; rr < 32; rr += 8)
    dst[(long)(c0 + ty + rr) * 512 + r0 + tx] = to_bf16(t[tx][ty + rr]);
}

__global__ __launch_bounds__(256) void convw_t(const float* __restrict__ src, u16* __restrict__ dst) {
  int id = blockIdx.x * 256 + threadIdx.x;
  if (id >= 512 * 3072) return;
  int o = id / 3072, r2 = id % 3072;
  int kp = r2 >> 10, i = r2 & 1023;
  dst[id] = to_bf16(src[(long)o * 3072 + i * 3 + kp]);
}

// y=0: a_mem->amt ; y=1: n_mem->nmt  (512x64, K padded)
__global__ __launch_bounds__(256) void memtrans2_k(const float* __restrict__ a,
    const float* __restrict__ n, u16* __restrict__ amt, u16* __restrict__ nmt) {
  int id = blockIdx.x * 256 + threadIdx.x;
  if (id >= 512 * 64) return;
  const float* src = blockIdx.y ? n : a;
  u16* dst = blockIdx.y ? nmt : amt;
  int nn = id >> 6, k = id & 63;
  dst[id] = (k < 60) ? to_bf16(src[(long)k * 512 + nn]) : (u16)0;
}

// [2][128][512] bf16, rows 60..127 zero  (MEMORY PHASE only — overlaps scores)
__global__ __launch_bounds__(256) void membpad_k(const float* __restrict__ a,
    const float* __restrict__ n, u16* __restrict__ dst) {
  int id = blockIdx.x * 256 + threadIdx.x;   // < 131072
  int mat = id >> 16, r2 = id & 65535;
  int nr = r2 >> 9, k = r2 & 511;
  const float* s = mat ? n : a;
  dst[id] = (nr < 60) ? to_bf16(s[(long)nr * 512 + k]) : (u16)0;
}

__global__ __launch_bounds__(256) void vtrans_k(const u16* __restrict__ qkv, u16* __restrict__ vt) {
  __shared__ u16 t[32][33];
  int z = blockIdx.z;
  int b = z >> 2, h2 = z & 3;
  int t0 = blockIdx.x * 32, d0 = blockIdx.y * 32;
  int tx = threadIdx.x & 31, ty = threadIdx.x >> 5;
  const u16* src = qkv + (long)b * 393216 + 1024 + h2 * 128;
  for (int rr = 0; rr < 32; rr += 8)
    t[ty + rr][tx] = src[(long)(t0 + ty + rr) * 1536 + d0 + tx];
  __syncthreads();
  u16* dst = vt + (long)z * 32768;
  for (int rr = 0; rr < 32; rr += 8)
    dst[(long)(d0 + ty + rr) * 256 + t0 + tx] = t[tx][ty + rr];
}

// vectorized fp32 -> bf16 convert, 8 elems/thread (n % 8 == 0)
__global__ __launch_bounds__(256) void cvt_k(const float* __restrict__ src, u16* __restrict__ dst, long n) {
  long i = ((long)blockIdx.x * 256 + threadIdx.x) * 8;
  if (i >= n) return;
  float4 f0 = ((const float4*)(src + i))[0];
  float4 f1 = ((const float4*)(src + i))[1];
  *(u16x8*)(dst + i) = pack8(f0, f1);
}

__global__ void zpage_k(u16* __restrict__ z) { z[threadIdx.x] = 0; }

// ================= layernorm: wave-per-row, fp32 in -> bf16 out =================
__global__ __launch_bounds__(256) void ln_k(const float* __restrict__ in,
    const float* __restrict__ g, const float* __restrict__ b, u16* __restrict__ out) {
  int wave = threadIdx.x >> 6, lane = threadIdx.x & 63;
  long row = (long)blockIdx.x * 4 + wave;
  const float* r = in + row * 512 + lane * 8;
  float4 x0 = ((const float4*)r)[0];
  float4 x1 = ((const float4*)r)[1];
  float s = x0.x + x0.y + x0.z + x0.w + x1.x + x1.y + x1.z + x1.w;
  for (int off = 32; off; off >>= 1) s += __shfl_xor(s, off);
  float mean = s * (1.f / 512.f);
  float d[8] = {x0.x - mean, x0.y - mean, x0.z - mean, x0.w - mean,
                x1.x - mean, x1.y - mean, x1.z - mean, x1.w - mean};
  float q = 0.f;
#pragma unroll
  for (int i = 0; i < 8; i++) q += d[i] * d[i];
  for (int off = 32; off; off >>= 1) q += __shfl_xor(q, off);
  float inv = rsqrtf(q * (1.f / 512.f) + 1e-5f);
  const float4* gp = (const float4*)(g + lane * 8);
  const float4* bp = (const float4*)(b + lane * 8);
  float4 g0 = gp[0], g1 = gp[1], b0 = bp[0], b1 = bp[1];
  float gv[8] = {g0.x, g0.y, g0.z, g0.w, g1.x, g1.y, g1.z, g1.w};
  float bv[8] = {b0.x, b0.y, b0.z, b0.w, b1.x, b1.y, b1.z, b1.w};
  u16x8 o;
#pragma unroll
  for (int i = 0; i < 8; i++) o[i] = to_bf16(d[i] * inv * gv[i] + bv[i]);
  *(u16x8*)(out + row * 512 + lane * 8) = o;
}

// ========== softmax: wave-per-row (rows of 256), fp32 in -> bf16 out ==========
__global__ __launch_bounds__(256) void softmax_k(const float* __restrict__ s, u16* __restrict__ d) {
  int wave = threadIdx.x >> 6, lane = threadIdx.x & 63;
  long row = (long)blockIdx.x * 4 + wave;
  const float* r = s + row * 256 + lane * 4;
  float4 v = *(const float4*)r;
  float mx = fmaxf(fmaxf(v.x, v.y), fmaxf(v.z, v.w));
  for (int off = 32; off; off >>= 1) mx = fmaxf(mx, __shfl_xor(mx, off));
  v.x = expf(v.x - mx); v.y = expf(v.y - mx); v.z = expf(v.z - mx); v.w = expf(v.w - mx);
  float sum = v.x + v.y + v.z + v.w;
  for (int off = 32; off; off >>= 1) sum += __shfl_xor(sum, off);
  float is = 1.f / sum;
  u16x4 o;
  o[0] = to_bf16(v.x * is); o[1] = to_bf16(v.y * is);
  o[2] = to_bf16(v.z * is); o[3] = to_bf16(v.w * is);
  *(u16x4*)(d + row * 256 + lane * 4) = o;
}

// y picks source block (stride 491520) -> out block {0,24576,16384,8192}
__global__ __launch_bounds__(256) void top4_k(const float* __restrict__ att, float* __restrict__ out) {
  int y = blockIdx.y;
  int i = blockIdx.x * 256 + threadIdx.x;
  if (i >= HBT) return;
  const float* a = att + (long)y * 491520 + (long)i * 60;
  float t0 = -1e30f, t1 = -1e30f, t2 = -1e30f, t3 = -1e30f;
  for (int k = 0; k < 60; k++) {
    float v = a[k];
    if (v > t0)      { t3 = t2; t2 = t1; t1 = t0; t0 = v; }
    else if (v > t1) { t3 = t2; t2 = t1; t1 = v; }
    else if (v > t2) { t3 = t2; t2 = v; }
    else if (v > t3) { t3 = v; }
  }
  int ooff = (y == 0) ? 0 : (4 - y) * 8192;
  out[ooff + i] = (t0 + t1 + t2 + t3) * 0.25f;
}

// ========== top-17 over 256: block-parallel iterative argmax; y selects source row-block
__global__ __launch_bounds__(256) void topk17_k(const float* __restrict__ tatt, int* __restrict__ idx) {
  int b = blockIdx.x, y = blockIdx.y, tid = threadIdx.x;
  __shared__ float sv[256];
  __shared__ int si[256];
  float v = tatt[(long)y * 8192 + (long)b * 256 + tid];
  int* ob = idx + y * 544 + b * 17;
  for (int s = 0; s < 17; s++) {
    sv[tid] = v; si[tid] = tid;
    __syncthreads();
    for (int off = 128; off > 0; off >>= 1) {
      if (tid < off) {
        float v2 = sv[tid + off]; int i2 = si[tid + off];
        if (v2 > sv[tid] || (v2 == sv[tid] && i2 < si[tid])) { sv[tid] = v2; si[tid] = i2; }
      }
      __syncthreads();
    }
    int win = si[0];
    if (tid == 0) ob[s] = win;
    if (tid == win) v = -1e30f;
    __syncthreads();
  }
}

__device__ inline void gmean_body(const float* feats, const int* idx, float* out, int b, int tid) {
  float s0 = 0.f, s1 = 0.f;
  for (int j = 0; j < 17; j++) {
    int t = idx[b * 17 + j];
    const float* r = feats + ((long)b * 256 + t) * 512;
    s0 += r[tid]; s1 += r[tid + 256];
  }
  out[(long)b * 512 + tid]       = s0 * (1.f / 17.f);
  out[(long)b * 512 + tid + 256] = s1 * (1.f / 17.f);
}

// y=0: (Ax, idxA)->NEG ; y=1: (Nx, idxN)->ANC ; y=2: (Ax, idxP)->POS
__global__ __launch_bounds__(256) void gmean3_k(const float* __restrict__ Ax,
    const float* __restrict__ Nx, const int* __restrict__ idx0, float* __restrict__ ob) {
  int b = blockIdx.x, y = blockIdx.y, tid = threadIdx.x;
  const float* feats = (y == 1) ? Nx : Ax;
  const int* idx = idx0 + y * 544;
  float* out = ob + (long)((y + 2) % 3) * 16384;
  gmean_body(feats, idx, out, b, tid);
}

// y=0: (f0=nnew, idxN)->ANEW ; y=1: (f1=R0, idxA)->NNEG
__global__ __launch_bounds__(256) void gmean2_k(const float* __restrict__ f0,
    const float* __restrict__ f1, const int* __restrict__ idx0, float* __restrict__ ob) {
  int b = blockIdx.x, y = blockIdx.y, tid = threadIdx.x;
  const float* feats = y ? f1 : f0;
  const int* idx = idx0 + (y == 0 ? 544 : 0);
  float* out = ob + (long)y * 16384;
  gmean_body(feats, idx, out, b, tid);
}

// vae: nnew may alias mu (elementwise read-before-write)
__global__ __launch_bounds__(256) void vae_k(const float* __restrict__ mu,
    const float* __restrict__ var, const float* __restrict__ eps,
    float* __restrict__ nnew, float* __restrict__ accum) {
  constexpr long N4 = HHf / 4;
  long stride = (long)gridDim.x * 256;
  float kle = 0.f;
  for (long i = (long)blockIdx.x * 256 + threadIdx.x; i < N4; i += stride) {
    float4 m4 = ((const float4*)mu)[i];
    float4 v4 = ((const float4*)var)[i];
    float4 e4 = ((const float4*)eps)[i];
    float4 o;
    float ev;
    ev = expf(v4.x); o.x = m4.x + e4.x * sqrtf(ev); kle += 1.f + v4.x - m4.x * m4.x - ev;
    ev = expf(v4.y); o.y = m4.y + e4.y * sqrtf(ev); kle += 1.f + v4.y - m4.y * m4.y - ev;
    ev = expf(v4.z); o.z = m4.z + e4.z * sqrtf(ev); kle += 1.f + v4.z - m4.z * m4.z - ev;
    ev = expf(v4.w); o.w = m4.w + e4.w * sqrtf(ev); kle += 1.f + v4.w - m4.w * m4.w - ev;
    ((float4*)nnew)[i] = o;
  }
  __shared__ float sm[256];
  float s = bred_sum(kle, sm, threadIdx.x);
  if (threadIdx.x == 0) atomicAdd(accum + 0, s);
}

__global__ __launch_bounds__(256) void tripcos_k(const float* __restrict__ anc,
    const float* __restrict__ pos, const float* __restrict__ neg, float* __restrict__ accum) {
  int b = blockIdx.x, tid = threadIdx.x;
  const float *a = anc + (long)b * 512, *p = pos + (long)b * 512, *n = neg + (long)b * 512;
  float a0 = a[tid], a1 = a[tid + 256], p0 = p[tid], p1 = p[tid + 256], n0 = n[tid], n1 = n[tid + 256];
  __shared__ float sm[256];
  float sa  = bred_sum(a0 * a0 + a1 * a1, sm, tid);
  float sp  = bred_sum(p0 * p0 + p1 * p1, sm, tid);
  float sn  = bred_sum(n0 * n0 + n1 * n1, sm, tid);
  float dot = bred_sum(a0 * n0 + a1 * n1, sm, tid);
  float na = sqrtf(sa), np_ = sqrtf(sp), nn = sqrtf(sn);
  float ina = 1.f / na, inp = 1.f / np_, inn = 1.f / nn;
  float d0 = a0 * ina - p0 * inp + 1e-6f, d1 = a1 * ina - p1 * inp + 1e-6f;
  float e0 = a0 * ina - n0 * inn + 1e-6f, e1 = a1 * ina - n1 * inn + 1e-6f;
  float dp2 = bred_sum(d0 * d0 + d1 * d1, sm, tid);
  float dn2 = bred_sum(e0 * e0 + e1 * e1, sm, tid);
  if (tid == 0) {
    float dp = sqrtf(dp2), dn = sqrtf(dn2);
    float t = dp - dn + 1.f;
    atomicAdd(accum + 1, t > 0.f ? t : 0.f);
    float c = 1.f - dot / (fmaxf(na, 1e-6f) * fmaxf(nn, 1e-6f));
    atomicAdd(accum + 2, c);
  }
}

__global__ __launch_bounds__(256) void dist_k(const float* __restrict__ anew,
    const float* __restrict__ nneg, float* __restrict__ accum) {
  int b = blockIdx.x, tid = threadIdx.x;
  const float *a = anew + (long)b * 512, *n = nneg + (long)b * 512;
  float a0 = a[tid], a1 = a[tid + 256], n0 = n[tid], n1 = n[tid + 256];
  __shared__ float sm[256];
  float sa = bred_sum(a0 * a0 + a1 * a1, sm, tid);
  float sn = bred_sum(n0 * n0 + n1 * n1, sm, tid);
  if (tid == 0) {
    float v = 100.f - sqrtf(sn) + sqrtf(sa);
    atomicAdd(accum + 3, v > 0.f ? v : 0.f);
  }
}

// float4 version: 4 elems/thread; grid 8192
__global__ __launch_bounds__(256) void xout_k(const float* __restrict__ emb,
    const float* __restrict__ nnew, const float* __restrict__ anm,
    const float* __restrict__ anew, const float* __restrict__ nam,
    float* __restrict__ xout) {
  long q = (long)blockIdx.x * 256 + threadIdx.x;   // float4 index, < 2097152
  long i = q * 4;
  long row = i >> 9;
  int d = (int)(i & 511);
  long o = row * 1024 + d;
  *(float4*)(xout + o) = ((const float4*)emb)[q];
  float4 v;
  if (i < HHf) {
    float4 a = ((const float4*)nnew)[q];
    float4 b = ((const float4*)anm)[q];
    v.x = a.x + b.x; v.y = a.y + b.y; v.z = a.z + b.z; v.w = a.w + b.w;
  } else {
    long q2 = q - HHf / 4;
    float4 a = ((const float4*)anew)[q2];
    float4 b = ((const float4*)nam)[q2];
    v.x = a.x + b.x; v.y = a.y + b.y; v.z = a.z + b.z; v.w = a.w + b.w;
  }
  *(float4*)(xout + o + 512) = v;
}

__global__ __launch_bounds__(256) void vfeat_k(const float* __restrict__ emb, float* __restrict__ vf) {
  __shared__ float tile[32][33];
  int b = blockIdx.z;
  int t0 = blockIdx.x * 32, d0 = blockIdx.y * 32;
  int tx = threadIdx.x & 31, ty = threadIdx.x >> 5;
  for (int r = 0; r < 32; r += 8)
    tile[ty + r][tx] = emb[((long)b * 256 + t0 + ty + r) * 512 + d0 + tx];
  __syncthreads();
  for (int r = 0; r < 32; r += 8)
    vf[((long)b * 512 + d0 + ty + r) * 256 + t0 + tx] = tile[tx][ty + r];
}

__global__ void init_k(float* accum) {
  accum[0] = 0.f; accum[1] = 0.f; accum[2] = 0.f; accum[3] = 0.f;
}

__global__ void fin_k(const float* __restrict__ accum, float* __restrict__ out) {
  out[0] = accum[1] * (1.f / 32.f);
  out[1] = -0.5f * accum[0] * (1.f / 16384.f);
  out[2] = accum[3] * (1.f / 32.f);
  out[OO_COS] = accum[2] * (1.f / 32.f);
}

static inline GP2 mk(const void* A, const void* B, const float* bias, void* C,
                     int M, int N, int K, int lda, int ldb, int ldc,
                     float scale = 1.f, int Hdiv = 1,
                     long sAb = 0, long sAh = 0, long sBb = 0, long sBh = 0,
                     long sCb = 0, long sCh = 0, const float* bias2 = nullptr,
                     u16* C2 = nullptr) {
  GP2 p; p.A = A; p.B = B; p.bias = bias; p.C = C; p.bias2 = bias2; p.C2 = C2;
  p.M = M; p.N = N; p.K = K; p.lda = lda; p.ldb = ldb; p.ldc = ldc;
  p.Hdiv = Hdiv; p.sAb = sAb; p.sAh = sAh; p.sBb = sBb; p.sBh = sBh;
  p.sCb = sCb; p.sCh = sCh; p.scale = scale;
  return p;
}

} // namespace

extern "C" void kernel_launch(void* const* d_in, const int* in_sizes, int n_in,
                              void* d_out, int out_size, void* d_ws, size_t ws_size,
                              hipStream_t stream) {
  const float* x      = (const float*)d_in[0];
  const float* epsi   = (const float*)d_in[1];
  const float* conv_w = (const float*)d_in[2];
  const float* conv_b = (const float*)d_in[3];
  const float* ln1_g  = (const float*)d_in[4];
  const float* ln1_b  = (const float*)d_in[5];
  const float* qkv_w  = (const float*)d_in[6];
  const float* out_w  = (const float*)d_in[7];
  const float* out_b  = (const float*)d_in[8];
  const float* ln2_g  = (const float*)d_in[9];
  const float* ln2_b  = (const float*)d_in[10];
  const float* ff1_w  = (const float*)d_in[11];
  const float* ff1_b  = (const float*)d_in[12];
  const float* ff2_w  = (const float*)d_in[13];
  const float* ff2_b  = (const float*)d_in[14];
  const float* a_mem  = (const float*)d_in[15];
  const float* n_mem  = (const float*)d_in[16];
  const float* mu_w   = (const float*)d_in[17];
  const float* mu_b   = (const float*)d_in[18];
  const float* var_w  = (const float*)d_in[19];
  const float* var_b  = (const float*)d_in[20];
  float* out = (float*)d_out;
  float* ws  = (float*)d_ws;

  const float ATTSCALE = 0.08838834764831845f;
  const float SIGSCALE = 0.04419417382415922f;

  float* h   = ws + F_H;
  u16* lnb   = (u16*)(ws + F_LNB);
  u16* qkvb  = (u16*)(ws + F_QKV);
  u16* vtb   = (u16*)(ws + F_VT);
  float* scf = ws + F_SC;
  u16* scb   = qkvb;                  // bf16 P (softmax out) reuses qkv region
  u16* wqkvT = (u16*)(ws + W_QKV);
  u16* woutT = (u16*)(ws + W_OUT);
  u16* wff1T = (u16*)(ws + W_FF1);
  u16* wff2T = (u16*)(ws + W_FF2);
  u16* wmuT  = (u16*)(ws + W_MU);
  u16* wconvT= (u16*)(ws + W_CONV);
  u16* amtT  = (u16*)(ws + W_AMT);
  u16* nmtT  = (u16*)(ws + W_NMT);
  u16* membT = (u16*)(ws + W_MEMB);   // [2][128][512] bf16 zero-padded (memory phase)
  u16* zpage = (u16*)(ws + Z_PG);
  u16* xb    = (u16*)(ws + F_QKV);    // x in bf16 (conv phase only)

  // ---- weight transposes ----
  wtrans_k<<<dim3(48, 16), 256, 0, stream>>>(qkv_w,          wqkvT,          512, 1536);
  wtrans_k<<<dim3(48, 16), 256, 0, stream>>>(qkv_w + 786432, wqkvT + 786432, 512, 1536);
  {
    WT8 w;
    w.s[0] = out_w;          w.doff[0] = 2 * W_OUT;
    w.s[1] = out_w + 262144; w.doff[1] = 2 * W_OUT + 262144;
    w.s[2] = ff1_w;          w.doff[2] = 2 * W_FF1;
    w.s[3] = ff1_w + 262144; w.doff[3] = 2 * W_FF1 + 262144;
    w.s[4] = ff2_w;          w.doff[4] = 2 * W_FF2;
    w.s[5] = ff2_w + 262144; w.doff[5] = 2 * W_FF2 + 262144;
    w.s[6] = mu_w;           w.doff[6] = 2 * W_MU;
    w.s[7] = var_w;          w.doff[7] = 2 * W_VAR;
    wt8_k<<<dim3(16, 16, 8), 256, 0, stream>>>(w, (u16*)ws);
  }
  convw_t<<<6144, 256, 0, stream>>>(conv_w, wconvT);
  memtrans2_k<<<dim3(128, 2), 256, 0, stream>>>(a_mem, n_mem, amtT, nmtT);

  // ---- conv + relu -> h (A via bf16 x + global_load_lds) ----
  cvt_k<<<8192, 256, 0, stream>>>(x, xb, 16777216);
  zpage_k<<<1, 256, 0, stream>>>(zpage);
  convm_k<<<dim3(128, 4), 256, 0, stream>>>(xb, zpage, wconvT, conv_b, h);

  // ---- transformer ----
  u16* hb = lnb;
  for (int i = 0; i < 2; i++) {
    ln_k<<<4096, 256, 0, stream>>>(h, ln1_g + i * 512, ln1_b + i * 512, lnb);
    {
      GP2 p = mk(lnb, wqkvT + (long)i * 786432, nullptr, qkvb, 16384, 1536, 512, 512, 512, 1536);
      mgemm_k<0, true, true, false, true, true><<<dim3(128, 12, 1), 256, 0, stream>>>(p);
    }
    vtrans_k<<<dim3(8, 4, 256), 256, 0, stream>>>(qkvb, vtb);
    {
      GP2 p = mk(qkvb, qkvb + 512, nullptr, scf, 256, 256, 128, 1536, 1536, 256,
                 ATTSCALE, 4, 393216, 128, 393216, 128, 262144, 65536);
      mgemm_k<0, true, true, false, false, true><<<dim3(2, 2, 256), 256, 0, stream>>>(p);
    }
    // softmax: fp32 scores -> bf16 P (overwrites dead Q/K rows; V already in vtb)
    softmax_k<<<16384, 256, 0, stream>>>(scf, scb);
    {
      GP2 p = mk(scb, vtb, nullptr, lnb, 256, 128, 256, 256, 256, 512,
                 1.f, 4, 262144, 65536, 131072, 32768, 131072, 128);
      mgemm_k<0, true, true, false, true, true><<<dim3(2, 1, 256), 256, 0, stream>>>(p);
    }
    {
      GP2 p = mk(lnb, woutT + (long)i * 262144, out_b + i * 512, h, 16384, 512, 512, 512, 512, 512);
      mgemm_k<0, true, true, true, false, true><<<dim3(128, 4, 1), 256, 0, stream>>>(p);
    }
    ln_k<<<4096, 256, 0, stream>>>(h, ln2_g + i * 512, ln2_b + i * 512, lnb);
    {
      GP2 p = mk(lnb, wff1T + (long)i * 262144, ff1_b + i * 512, qkvb, 16384, 512, 512, 512, 512, 512);
      mgemm_k<1, true, true, false, true, true><<<dim3(128, 4, 1), 256, 0, stream>>>(p);
    }
    if (i == 0) {
      GP2 p = mk(qkvb, wff2T, ff2_b, h, 16384, 512, 512, 512, 512, 512);
      mgemm_k<0, true, true, true, false, true><<<dim3(128, 4, 1), 256, 0, stream>>>(p);
    } else {
      // layer 1 ff2: fused dual write — fp32 h (residual acc) + bf16 hb
      GP2 p = mk(qkvb, wff2T + 262144, ff2_b + 512, h, 16384, 512, 512, 512, 512, 512,
                 1.f, 1, 0, 0, 0, 0, 0, 0, nullptr, hb);
      mgemm_k<0, true, true, true, false, true, true><<<dim3(128, 4, 1), 256, 0, stream>>>(p);
    }
  }

  // ---- memory phase (hb already written by fused ff2 epilogue) ----
  membpad_k<<<512, 256, 0, stream>>>(a_mem, n_mem, membT);
  const float* Nx = h;
  const float* Ax = h + HHf;
  const u16* Axb = hb + HHf;
  float* attA  = ws + F_ATT;
  float* attN  = ws + F_ATT + 1474560;

  // 4 att GEMMs, one GL launch: bb picks Ax/Nx, hh picks a_mem/n_mem (padded B)
  {
    GP2 p = mk(Axb, membT, nullptr, attA, HBT, 60, 512, 512, 512, 60, SIGSCALE,
               2, -(long)HHf, 0, 0, 65536, 983040, 491520);
    mgemm_k<2, true, true, false, false, true><<<dim3(64, 1, 4), 256, 0, stream>>>(p);
  }

  // merged 4-way top4
  top4_k<<<dim3(32, 4), 256, 0, stream>>>(attA, out + OO_AATT);

  // 4 aug GEMMs in one launch; C order: augA, augNA, augAN, augN
  u16* augb = (u16*)(ws + F_AUG);
  u16* augA  = augb;
  u16* augN  = augb + 3 * HHf;
  {
    GP2 p = mk(attA, amtT, nullptr, augA, HBT, 512, 60, 60, 64, 512, 1.f,
               2, 983040, 491520, 0, 32768, 2 * HHf, HHf);
    mgemm_k<0, false, true, false, true, false><<<dim3(64, 4, 4), 256, 0, stream>>>(p);
  }

  float* accum = ws + O_ACC;
  int* idxA = (int*)(ws + O_IDX);
  init_k<<<1, 1, 0, stream>>>(accum);

  topk17_k<<<dim3(32, 3), 256, 0, stream>>>(out + OO_AATT, idxA);
  gmean3_k<<<dim3(32, 3), 256, 0, stream>>>(Ax, Nx, idxA, ws + O_ANC);
  tripcos_k<<<32, 256, 0, stream>>>(ws + O_ANC, ws + O_POS, ws + O_NEG, accum);

  // round1: augN @ {mu,var} in one launch
  {
    GP2 p = mk(augN, wmuT, mu_b, ws + F_MU, HBT, 512, 512, 512, 512, 512, 1.f,
               2, 0, 0, 0, 262144, 0, 4194304, var_b);
    mgemm_k<0, true, true, false, false, true><<<dim3(64, 4, 2), 256, 0, stream>>>(p);
  }
  vae_k<<<512, 256, 0, stream>>>(ws + F_MU, ws + F_VAR, epsi, ws + F_MU, accum);

  // round2: {augA, augNA, augAN} @ mu -> {R0=anew, R1=nam, R2=anm}
  {
    GP2 p = mk(augA, wmuT, mu_b, ws + F_R0, HBT, 512, 512, 512, 512, 512, 1.f,
               1, HHf, 0, 0, 0, 4194304, 0);
    mgemm_k<0, true, true, false, false, true><<<dim3(64, 4, 3), 256, 0, stream>>>(p);
  }

  gmean2_k<<<dim3(32, 2), 256, 0, stream>>>(ws + F_MU, ws + F_R0, idxA, ws + O_ANEW);
  dist_k<<<32, 256, 0, stream>>>(ws + O_ANEW, ws + O_NNEG, accum);

  xout_k<<<8192, 256, 0, stream>>>(h, ws + F_MU, ws + F_R2, ws + F_R0, ws + F_R1,
                                   out + OO_XOUT);
  vfeat_k<<<dim3(8, 16, 64), 256, 0, stream>>>(h, out + OO_VFEAT);
  fin_k<<<1, 1, 0, stream>>>(accum, out);
}